// Round 1
// baseline (25421.846 us; speedup 1.0000x reference)
//
#include <hip/hip_runtime.h>
#include <hip/hip_bf16.h>

#define NQ 200
#define PFX 5
#define NPATCH 1600
#define NT 1805
#define DM 1024
#define NHEAD 16
#define DHEAD 64
#define NBLK 4
#define NCLS 151

__device__ __forceinline__ float gelu_f(float x) {
  return 0.5f * x * (1.0f + erff(x * 0.7071067811865476f));
}

// ---------------- concat: x = [q_weight ; x_tokens] ----------------
__global__ __launch_bounds__(256) void concat_kernel(const float* __restrict__ qw,
    const float* __restrict__ xt, float* __restrict__ x) {
  int idx = blockIdx.x * 256 + threadIdx.x;
  if (idx >= NT * DM) return;
  int n = idx >> 10;
  x[idx] = (n < NQ) ? qw[idx] : xt[idx - NQ * DM];
}

// ---------------- LayerNorm over D=1024, one block per row ----------------
__global__ __launch_bounds__(256) void ln_kernel(const float* __restrict__ in,
    const float* __restrict__ g, const float* __restrict__ b, float* __restrict__ out) {
  const int row = blockIdx.x;
  const int tid = threadIdx.x;
  const float* x = in + (size_t)row * DM;
  float v[4];
#pragma unroll
  for (int i = 0; i < 4; ++i) v[i] = x[tid + (i << 8)];
  float s = v[0] + v[1] + v[2] + v[3];
  __shared__ float red[4];
  __shared__ float red2[4];
#pragma unroll
  for (int off = 32; off; off >>= 1) s += __shfl_down(s, off, 64);
  if ((tid & 63) == 0) red[tid >> 6] = s;
  __syncthreads();
  float mean = (red[0] + red[1] + red[2] + red[3]) * (1.0f / DM);
  float sq = 0.f;
#pragma unroll
  for (int i = 0; i < 4; ++i) { float d = v[i] - mean; sq += d * d; }
#pragma unroll
  for (int off = 32; off; off >>= 1) sq += __shfl_down(sq, off, 64);
  if ((tid & 63) == 0) red2[tid >> 6] = sq;
  __syncthreads();
  float var = (red2[0] + red2[1] + red2[2] + red2[3]) * (1.0f / DM);
  float inv = 1.0f / sqrtf(var + 1e-6f);
  float* y = out + (size_t)row * DM;
#pragma unroll
  for (int i = 0; i < 4; ++i) {
    int d = tid + (i << 8);
    y[d] = (v[i] - mean) * inv * g[d] + b[d];
  }
}

// ---------------- generic fp32 GEMM: C = act(A@B + bias) ----------------
// A: M x K row-major. B: (K x Nc) row-major, or TRANSB: (Nc x K) row-major.
// ACT: 0 = none, 1 = exact gelu.
template <int TRANSB, int ACT>
__global__ __launch_bounds__(256) void gemm_kernel(const float* __restrict__ A,
    const float* __restrict__ B, const float* __restrict__ bias, float* __restrict__ C,
    int M, int Nc, int K) {
  __shared__ float As[16][68];  // [k][m], pad to 68 -> 16B-aligned rows
  __shared__ float Bs[16][68];  // [k][n]
  const int bm = blockIdx.y * 64;
  const int bn = blockIdx.x * 64;
  const int tid = threadIdx.x;
  const int tm = (tid >> 4) << 2;
  const int tn = (tid & 15) << 2;
  float acc[4][4] = {};
  for (int k0 = 0; k0 < K; k0 += 16) {
#pragma unroll
    for (int i = 0; i < 4; ++i) {
      int e = tid + (i << 8);
      int r = e >> 4, kk = e & 15;
      int gm = bm + r;
      As[kk][r] = (gm < M) ? A[(size_t)gm * K + (k0 + kk)] : 0.f;
      if (TRANSB) {
        int gn = bn + r;
        Bs[kk][r] = (gn < Nc) ? B[(size_t)gn * K + (k0 + kk)] : 0.f;
      } else {
        int kk2 = e >> 6, n2 = e & 63;
        int gn = bn + n2;
        Bs[kk2][n2] = (gn < Nc) ? B[(size_t)(k0 + kk2) * Nc + gn] : 0.f;
      }
    }
    __syncthreads();
#pragma unroll
    for (int kk = 0; kk < 16; ++kk) {
      float a[4], b[4];
#pragma unroll
      for (int i = 0; i < 4; ++i) a[i] = As[kk][tm + i];
#pragma unroll
      for (int j = 0; j < 4; ++j) b[j] = Bs[kk][tn + j];
#pragma unroll
      for (int i = 0; i < 4; ++i)
#pragma unroll
        for (int j = 0; j < 4; ++j) acc[i][j] = fmaf(a[i], b[j], acc[i][j]);
    }
    __syncthreads();
  }
#pragma unroll
  for (int i = 0; i < 4; ++i) {
    int gm = bm + tm + i;
    if (gm >= M) continue;
#pragma unroll
    for (int j = 0; j < 4; ++j) {
      int gn = bn + tn + j;
      if (gn >= Nc) continue;
      float v = acc[i][j] + (bias ? bias[gn] : 0.f);
      if (ACT == 1) v = gelu_f(v);
      C[(size_t)gm * Nc + gn] = v;
    }
  }
}

// ---------------- attention: one block per (row n, head h) ----------------
// qkv: NT x 3072 (q|k|v each 1024, head-major DHEAD chunks)
// mlog: mask logits for this layer (NQ x NPATCH); bias = (mlog>0 ? 0 : -1e9)
// applied at rows n<NQ, cols j>=NQ+PFX.  o: NT x DM (heads concatenated).
__global__ __launch_bounds__(256) void attn_kernel(const float* __restrict__ qkv,
    const float* __restrict__ mlog, float* __restrict__ o) {
  const int n = blockIdx.x;
  const int h = blockIdx.y;
  const int tid = threadIdx.x;
  __shared__ float sq[DHEAD];
  __shared__ float s[NT];
  __shared__ float red[4];
  __shared__ float red2[4];
  __shared__ float part[4][DHEAD];
  if (tid < DHEAD) sq[tid] = qkv[(size_t)n * (3 * DM) + h * DHEAD + tid];
  __syncthreads();
  for (int j = tid; j < NT; j += 256) {
    const float* kr = qkv + (size_t)j * (3 * DM) + DM + h * DHEAD;
    float acc = 0.f;
#pragma unroll
    for (int d = 0; d < DHEAD; ++d) acc = fmaf(sq[d], kr[d], acc);
    acc *= 0.125f;  // 1/sqrt(64)
    if (n < NQ && j >= NQ + PFX) {
      float m = mlog[(size_t)n * NPATCH + (j - NQ - PFX)];
      if (!(m > 0.f)) acc -= 1e9f;
    }
    s[j] = acc;
  }
  __syncthreads();
  float mx = -3.0e38f;
  for (int j = tid; j < NT; j += 256) mx = fmaxf(mx, s[j]);
#pragma unroll
  for (int off = 32; off; off >>= 1) mx = fmaxf(mx, __shfl_down(mx, off, 64));
  if ((tid & 63) == 0) red[tid >> 6] = mx;
  __syncthreads();
  mx = fmaxf(fmaxf(red[0], red[1]), fmaxf(red[2], red[3]));
  float sum = 0.f;
  for (int j = tid; j < NT; j += 256) {
    float e = expf(s[j] - mx);
    s[j] = e;
    sum += e;
  }
#pragma unroll
  for (int off = 32; off; off >>= 1) sum += __shfl_down(sum, off, 64);
  if ((tid & 63) == 0) red2[tid >> 6] = sum;
  __syncthreads();
  sum = red2[0] + red2[1] + red2[2] + red2[3];
  float inv = 1.0f / sum;
  const int d = tid & 63, c = tid >> 6;
  float acc = 0.f;
  for (int j = c; j < NT; j += 4)
    acc = fmaf(s[j], qkv[(size_t)j * (3 * DM) + 2 * DM + h * DHEAD + d], acc);
  part[c][d] = acc;
  __syncthreads();
  if (tid < DHEAD)
    o[(size_t)n * DM + h * DHEAD + tid] =
        (part[0][tid] + part[1][tid] + part[2][tid] + part[3][tid]) * inv;
}

// ---------------- residual with layer-scale: x += ls * y ----------------
__global__ __launch_bounds__(256) void resid_kernel(float* __restrict__ x,
    const float* __restrict__ y, const float* __restrict__ ls) {
  int idx = blockIdx.x * 256 + threadIdx.x;
  if (idx >= NT * DM) return;
  int d = idx & (DM - 1);
  x[idx] = fmaf(ls[d], y[idx], x[idx]);
}

extern "C" void kernel_launch(void* const* d_in, const int* in_sizes, int n_in,
                              void* d_out, int out_size, void* d_ws, size_t ws_size,
                              hipStream_t stream) {
  const float* x_tokens = (const float*)d_in[0];
  const float* q_weight = (const float*)d_in[1];
  const float* norm_g   = (const float*)d_in[2];
  const float* norm_b   = (const float*)d_in[3];
  const float* class_W  = (const float*)d_in[4];
  const float* class_b  = (const float*)d_in[5];
  const float* mask_W1  = (const float*)d_in[6];
  const float* mask_b1  = (const float*)d_in[7];
  const float* mask_W2  = (const float*)d_in[8];
  const float* mask_b2  = (const float*)d_in[9];
  const float* mask_W3  = (const float*)d_in[10];
  const float* mask_b3  = (const float*)d_in[11];
  const float* ln1_g    = (const float*)d_in[12];
  const float* ln1_b    = (const float*)d_in[13];
  const float* ln2_g    = (const float*)d_in[14];
  const float* ln2_b    = (const float*)d_in[15];
  const float* qkv_W    = (const float*)d_in[16];
  const float* qkv_b    = (const float*)d_in[17];
  const float* proj_W   = (const float*)d_in[18];
  const float* proj_b   = (const float*)d_in[19];
  const float* ls1      = (const float*)d_in[20];
  const float* ls2      = (const float*)d_in[21];
  const float* fc1_W    = (const float*)d_in[22];
  const float* fc1_b    = (const float*)d_in[23];
  const float* fc2_W    = (const float*)d_in[24];
  const float* fc2_b    = (const float*)d_in[25];

  float* out = (float*)d_out;
  float* ws = (float*)d_ws;
  float* x      = ws;                              // NT*DM
  float* lnbuf  = x + (size_t)NT * DM;             // NT*DM
  float* attn_o = lnbuf + (size_t)NT * DM;         // NT*DM
  float* tmp    = attn_o + (size_t)NT * DM;        // NT*DM
  float* f1     = tmp + (size_t)NT * DM;           // NQ*DM
  float* f2     = f1 + (size_t)NQ * DM;            // NQ*DM
  float* big    = f2 + (size_t)NQ * DM;            // NT*4096 (qkv / fc1 out)

  auto ggrid = [](int M, int Nc) { return dim3((Nc + 63) / 64, (M + 63) / 64); };
  const int ELEM_GRID = (NT * DM + 255) / 256;

  concat_kernel<<<ELEM_GRID, 256, 0, stream>>>(q_weight, x_tokens, x);

  for (int i = 0; i <= NBLK; ++i) {
    // ---- predict on LN(x) with shared norm ----
    ln_kernel<<<NT, 256, 0, stream>>>(x, norm_g, norm_b, lnbuf);
    float* mask_i = out + (size_t)i * NQ * NPATCH;
    float* cls_i  = out + (size_t)5 * NQ * NPATCH + (size_t)i * NQ * NCLS;
    gemm_kernel<0, 1><<<ggrid(NQ, DM), 256, 0, stream>>>(lnbuf, mask_W1, mask_b1, f1, NQ, DM, DM);
    gemm_kernel<0, 1><<<ggrid(NQ, DM), 256, 0, stream>>>(f1, mask_W2, mask_b2, f2, NQ, DM, DM);
    gemm_kernel<0, 0><<<ggrid(NQ, DM), 256, 0, stream>>>(f2, mask_W3, mask_b3, f1, NQ, DM, DM);
    // mask_logits = f @ patch^T, patch = lnbuf rows [NQ+PFX, NT)
    gemm_kernel<1, 0><<<ggrid(NQ, NPATCH), 256, 0, stream>>>(
        f1, lnbuf + (size_t)(NQ + PFX) * DM, nullptr, mask_i, NQ, NPATCH, DM);
    gemm_kernel<0, 0><<<ggrid(NQ, NCLS), 256, 0, stream>>>(lnbuf, class_W, class_b, cls_i, NQ, NCLS, DM);
    if (i == NBLK) break;

    // ---- transformer block i ----
    ln_kernel<<<NT, 256, 0, stream>>>(x, ln1_g + i * DM, ln1_b + i * DM, lnbuf);
    gemm_kernel<0, 0><<<ggrid(NT, 3 * DM), 256, 0, stream>>>(
        lnbuf, qkv_W + (size_t)i * DM * 3 * DM, qkv_b + i * 3 * DM, big, NT, 3 * DM, DM);
    attn_kernel<<<dim3(NT, NHEAD), 256, 0, stream>>>(big, mask_i, attn_o);
    gemm_kernel<0, 0><<<ggrid(NT, DM), 256, 0, stream>>>(
        attn_o, proj_W + (size_t)i * DM * DM, proj_b + i * DM, tmp, NT, DM, DM);
    resid_kernel<<<ELEM_GRID, 256, 0, stream>>>(x, tmp, ls1 + i * DM);
    ln_kernel<<<NT, 256, 0, stream>>>(x, ln2_g + i * DM, ln2_b + i * DM, lnbuf);
    gemm_kernel<0, 1><<<ggrid(NT, 4 * DM), 256, 0, stream>>>(
        lnbuf, fc1_W + (size_t)i * DM * 4 * DM, fc1_b + i * 4 * DM, big, NT, 4 * DM, DM);
    gemm_kernel<0, 0><<<ggrid(NT, DM), 256, 0, stream>>>(
        big, fc2_W + (size_t)i * 4 * DM * DM, fc2_b + i * DM, tmp, NT, DM, 4 * DM);
    resid_kernel<<<ELEM_GRID, 256, 0, stream>>>(x, tmp, ls2 + i * DM);
  }
}

// Round 2
// 15081.253 us; speedup vs baseline: 1.6857x; 1.6857x over previous
//
#include <hip/hip_runtime.h>
#include <hip/hip_bf16.h>

#define NQ 200
#define PFX 5
#define NPATCH 1600
#define NT 1805
#define DM 1024
#define NHEAD 16
#define DHEAD 64
#define NBLK 4
#define NCLS 151
#define NKT 29  // ceil(1805/64)

__device__ __forceinline__ float gelu_f(float x) {
  return 0.5f * x * (1.0f + erff(x * 0.7071067811865476f));
}

// ---------------- concat: x = [q_weight ; x_tokens] ----------------
__global__ __launch_bounds__(256) void concat_kernel(const float* __restrict__ qw,
    const float* __restrict__ xt, float* __restrict__ x) {
  int idx = blockIdx.x * 256 + threadIdx.x;
  if (idx >= NT * DM) return;
  int n = idx >> 10;
  x[idx] = (n < NQ) ? qw[idx] : xt[idx - NQ * DM];
}

// ---------------- LayerNorm over D=1024, one block per row ----------------
__global__ __launch_bounds__(256) void ln_kernel(const float* __restrict__ in,
    const float* __restrict__ g, const float* __restrict__ b, float* __restrict__ out) {
  const int row = blockIdx.x;
  const int tid = threadIdx.x;
  const float* x = in + (size_t)row * DM;
  float v[4];
#pragma unroll
  for (int i = 0; i < 4; ++i) v[i] = x[tid + (i << 8)];
  float s = v[0] + v[1] + v[2] + v[3];
  __shared__ float red[4];
  __shared__ float red2[4];
#pragma unroll
  for (int off = 32; off; off >>= 1) s += __shfl_down(s, off, 64);
  if ((tid & 63) == 0) red[tid >> 6] = s;
  __syncthreads();
  float mean = (red[0] + red[1] + red[2] + red[3]) * (1.0f / DM);
  float sq = 0.f;
#pragma unroll
  for (int i = 0; i < 4; ++i) { float d = v[i] - mean; sq += d * d; }
#pragma unroll
  for (int off = 32; off; off >>= 1) sq += __shfl_down(sq, off, 64);
  if ((tid & 63) == 0) red2[tid >> 6] = sq;
  __syncthreads();
  float var = (red2[0] + red2[1] + red2[2] + red2[3]) * (1.0f / DM);
  float inv = 1.0f / sqrtf(var + 1e-6f);
  float* y = out + (size_t)row * DM;
#pragma unroll
  for (int i = 0; i < 4; ++i) {
    int d = tid + (i << 8);
    y[d] = (v[i] - mean) * inv * g[d] + b[d];
  }
}

// ---------------- generic fp32 GEMM: C = act(A@B + bias) ----------------
template <int TRANSB, int ACT>
__global__ __launch_bounds__(256) void gemm_kernel(const float* __restrict__ A,
    const float* __restrict__ B, const float* __restrict__ bias, float* __restrict__ C,
    int M, int Nc, int K) {
  __shared__ float As[16][68];
  __shared__ float Bs[16][68];
  const int bm = blockIdx.y * 64;
  const int bn = blockIdx.x * 64;
  const int tid = threadIdx.x;
  const int tm = (tid >> 4) << 2;
  const int tn = (tid & 15) << 2;
  float acc[4][4] = {};
  for (int k0 = 0; k0 < K; k0 += 16) {
#pragma unroll
    for (int i = 0; i < 4; ++i) {
      int e = tid + (i << 8);
      int r = e >> 4, kk = e & 15;
      int gm = bm + r;
      As[kk][r] = (gm < M) ? A[(size_t)gm * K + (k0 + kk)] : 0.f;
      if (TRANSB) {
        int gn = bn + r;
        Bs[kk][r] = (gn < Nc) ? B[(size_t)gn * K + (k0 + kk)] : 0.f;
      } else {
        int kk2 = e >> 6, n2 = e & 63;
        int gn = bn + n2;
        Bs[kk2][n2] = (gn < Nc) ? B[(size_t)(k0 + kk2) * Nc + gn] : 0.f;
      }
    }
    __syncthreads();
#pragma unroll
    for (int kk = 0; kk < 16; ++kk) {
      float a[4], b[4];
#pragma unroll
      for (int i = 0; i < 4; ++i) a[i] = As[kk][tm + i];
#pragma unroll
      for (int j = 0; j < 4; ++j) b[j] = Bs[kk][tn + j];
#pragma unroll
      for (int i = 0; i < 4; ++i)
#pragma unroll
        for (int j = 0; j < 4; ++j) acc[i][j] = fmaf(a[i], b[j], acc[i][j]);
    }
    __syncthreads();
  }
#pragma unroll
  for (int i = 0; i < 4; ++i) {
    int gm = bm + tm + i;
    if (gm >= M) continue;
#pragma unroll
    for (int j = 0; j < 4; ++j) {
      int gn = bn + tn + j;
      if (gn >= Nc) continue;
      float v = acc[i][j] + (bias ? bias[gn] : 0.f);
      if (ACT == 1) v = gelu_f(v);
      C[(size_t)gm * Nc + gn] = v;
    }
  }
}

// ---------------- flash attention: block = (q-tile of 64, head) ----------------
// qkv: NT x 3072 (q|k|v). Online softmax; P buffered in dead K tile.
// LDS tiles XOR-swizzled at float4 granularity: block bi of row r at bi^(r>>2).
__global__ __launch_bounds__(256) void fattn_kernel(const float* __restrict__ qkv,
    const float* __restrict__ mlog, float* __restrict__ o) {
  const int q0 = blockIdx.x * 64;
  const int h = blockIdx.y;
  const int tid = threadIdx.x;
  const int qg = tid >> 4;   // 0..15, owns q rows 4qg..4qg+3
  const int kg = tid & 15;   // 0..15, owns k cols 4kg..4kg+3 (phase A) / d cols (phase C)

  __shared__ float Qs[64][64];
  __shared__ float Ks[64][64];  // K tile; reused as P buffer after phase A
  __shared__ float Vs[64][64];
  __shared__ float rm[64], rl[64], rf[64];

  // ---- stage Q tile (swizzled) + init state ----
#pragma unroll
  for (int ii = 0; ii < 4; ++ii) {
    int e = tid + (ii << 8);
    int r = e >> 4, bi = e & 15;
    int gq = q0 + r;
    float4 qv = make_float4(0.f, 0.f, 0.f, 0.f);
    if (gq < NT) qv = *(const float4*)(qkv + (size_t)gq * 3072 + h * 64 + bi * 4);
    *(float4*)&Qs[r][((bi ^ (r >> 2)) & 15) * 4] = qv;
  }
  if (tid < 64) { rm[tid] = -3.0e38f; rl[tid] = 0.f; }
  float o_acc[4][4] = {};

  for (int kt = 0; kt < NKT; ++kt) {
    __syncthreads();  // prev phase C done reading Ks(P)/Vs
    // ---- stage K,V tiles (swizzled) ----
#pragma unroll
    for (int ii = 0; ii < 4; ++ii) {
      int e = tid + (ii << 8);
      int r = e >> 4, bi = e & 15;
      int gk = kt * 64 + r;
      float4 kv = make_float4(0.f, 0.f, 0.f, 0.f), vv = kv;
      if (gk < NT) {
        kv = *(const float4*)(qkv + (size_t)gk * 3072 + 1024 + h * 64 + bi * 4);
        vv = *(const float4*)(qkv + (size_t)gk * 3072 + 2048 + h * 64 + bi * 4);
      }
      int sb = ((bi ^ (r >> 2)) & 15) * 4;
      *(float4*)&Ks[r][sb] = kv;
      *(float4*)&Vs[r][sb] = vv;
    }
    __syncthreads();

    // ---- phase A: scores (regs) ----
    float s[4][4] = {};
#pragma unroll
    for (int d4 = 0; d4 < 16; ++d4) {
      float4 q[4], k[4];
#pragma unroll
      for (int i = 0; i < 4; ++i) q[i] = *(const float4*)&Qs[qg * 4 + i][((d4 ^ qg) & 15) * 4];
#pragma unroll
      for (int j = 0; j < 4; ++j) k[j] = *(const float4*)&Ks[kg * 4 + j][((d4 ^ kg) & 15) * 4];
#pragma unroll
      for (int i = 0; i < 4; ++i)
#pragma unroll
        for (int j = 0; j < 4; ++j) {
          s[i][j] = fmaf(q[i].x, k[j].x, s[i][j]);
          s[i][j] = fmaf(q[i].y, k[j].y, s[i][j]);
          s[i][j] = fmaf(q[i].z, k[j].z, s[i][j]);
          s[i][j] = fmaf(q[i].w, k[j].w, s[i][j]);
        }
    }
    // scale + mask bias + OOB
#pragma unroll
    for (int i = 0; i < 4; ++i) {
      int gq = q0 + qg * 4 + i;
#pragma unroll
      for (int j = 0; j < 4; ++j) {
        int gk = kt * 64 + kg * 4 + j;
        if (gk >= NT) { s[i][j] = -3.0e38f; continue; }
        s[i][j] *= 0.125f;
        if (gq < NQ && gk >= NQ + PFX) {
          float m = mlog[(size_t)gq * NPATCH + (gk - NQ - PFX)];
          if (!(m > 0.f)) s[i][j] -= 1e9f;
        }
      }
    }

    // ---- phase B: online softmax (regs + shfl over 16-lane kg group) ----
    float mnew[4], f[4], psum[4];
#pragma unroll
    for (int i = 0; i < 4; ++i) {
      float tm = fmaxf(fmaxf(s[i][0], s[i][1]), fmaxf(s[i][2], s[i][3]));
#pragma unroll
      for (int m2 = 1; m2 < 16; m2 <<= 1) tm = fmaxf(tm, __shfl_xor(tm, m2, 64));
      float rmold = rm[qg * 4 + i];
      mnew[i] = fmaxf(rmold, tm);
      f[i] = expf(rmold - mnew[i]);
      float ps = 0.f;
#pragma unroll
      for (int j = 0; j < 4; ++j) {
        s[i][j] = expf(s[i][j] - mnew[i]);  // now P
        ps += s[i][j];
      }
#pragma unroll
      for (int m2 = 1; m2 < 16; m2 <<= 1) ps += __shfl_xor(ps, m2, 64);
      psum[i] = ps;
    }
    __syncthreads();  // all Ks reads done; safe to overwrite with P

    // ---- write P into Ks buffer; kg==0 updates row state ----
#pragma unroll
    for (int i = 0; i < 4; ++i) {
      int r = qg * 4 + i;
      *(float4*)&Ks[r][((kg ^ qg) & 15) * 4] = make_float4(s[i][0], s[i][1], s[i][2], s[i][3]);
    }
    if (kg == 0) {
#pragma unroll
      for (int i = 0; i < 4; ++i) {
        int r = qg * 4 + i;
        rm[r] = mnew[i];
        rl[r] = rl[r] * f[i] + psum[i];
        rf[r] = f[i];
      }
    }
    __syncthreads();

    // ---- phase C: O = O*rf + P@V ----
#pragma unroll
    for (int i = 0; i < 4; ++i) {
      float fi = rf[qg * 4 + i];
#pragma unroll
      for (int c = 0; c < 4; ++c) o_acc[i][c] *= fi;
    }
#pragma unroll
    for (int k4 = 0; k4 < 16; ++k4) {
      float4 p[4], v[4];
#pragma unroll
      for (int i = 0; i < 4; ++i) p[i] = *(const float4*)&Ks[qg * 4 + i][((k4 ^ qg) & 15) * 4];
#pragma unroll
      for (int j = 0; j < 4; ++j) v[j] = *(const float4*)&Vs[k4 * 4 + j][((kg ^ k4) & 15) * 4];
#pragma unroll
      for (int i = 0; i < 4; ++i) {
        const float* pp = (const float*)&p[i];
#pragma unroll
        for (int j = 0; j < 4; ++j) {
          const float* vp = (const float*)&v[j];
#pragma unroll
          for (int c = 0; c < 4; ++c) o_acc[i][c] = fmaf(pp[j], vp[c], o_acc[i][c]);
        }
      }
    }
  }

  // ---- epilogue: normalize + store ----
#pragma unroll
  for (int i = 0; i < 4; ++i) {
    int gq = q0 + qg * 4 + i;
    if (gq >= NT) continue;
    float inv = 1.0f / rl[qg * 4 + i];
    float4 ov = make_float4(o_acc[i][0] * inv, o_acc[i][1] * inv, o_acc[i][2] * inv, o_acc[i][3] * inv);
    *(float4*)(o + (size_t)gq * DM + h * 64 + kg * 4) = ov;
  }
}

// ---------------- residual with layer-scale: x += ls * y ----------------
__global__ __launch_bounds__(256) void resid_kernel(float* __restrict__ x,
    const float* __restrict__ y, const float* __restrict__ ls) {
  int idx = blockIdx.x * 256 + threadIdx.x;
  if (idx >= NT * DM) return;
  int d = idx & (DM - 1);
  x[idx] = fmaf(ls[d], y[idx], x[idx]);
}

extern "C" void kernel_launch(void* const* d_in, const int* in_sizes, int n_in,
                              void* d_out, int out_size, void* d_ws, size_t ws_size,
                              hipStream_t stream) {
  const float* x_tokens = (const float*)d_in[0];
  const float* q_weight = (const float*)d_in[1];
  const float* norm_g   = (const float*)d_in[2];
  const float* norm_b   = (const float*)d_in[3];
  const float* class_W  = (const float*)d_in[4];
  const float* class_b  = (const float*)d_in[5];
  const float* mask_W1  = (const float*)d_in[6];
  const float* mask_b1  = (const float*)d_in[7];
  const float* mask_W2  = (const float*)d_in[8];
  const float* mask_b2  = (const float*)d_in[9];
  const float* mask_W3  = (const float*)d_in[10];
  const float* mask_b3  = (const float*)d_in[11];
  const float* ln1_g    = (const float*)d_in[12];
  const float* ln1_b    = (const float*)d_in[13];
  const float* ln2_g    = (const float*)d_in[14];
  const float* ln2_b    = (const float*)d_in[15];
  const float* qkv_W    = (const float*)d_in[16];
  const float* qkv_b    = (const float*)d_in[17];
  const float* proj_W   = (const float*)d_in[18];
  const float* proj_b   = (const float*)d_in[19];
  const float* ls1      = (const float*)d_in[20];
  const float* ls2      = (const float*)d_in[21];
  const float* fc1_W    = (const float*)d_in[22];
  const float* fc1_b    = (const float*)d_in[23];
  const float* fc2_W    = (const float*)d_in[24];
  const float* fc2_b    = (const float*)d_in[25];

  float* out = (float*)d_out;
  float* ws = (float*)d_ws;
  float* x      = ws;
  float* lnbuf  = x + (size_t)NT * DM;
  float* attn_o = lnbuf + (size_t)NT * DM;
  float* tmp    = attn_o + (size_t)NT * DM;
  float* f1     = tmp + (size_t)NT * DM;
  float* f2     = f1 + (size_t)NQ * DM;
  float* big    = f2 + (size_t)NQ * DM;

  auto ggrid = [](int M, int Nc) { return dim3((Nc + 63) / 64, (M + 63) / 64); };
  const int ELEM_GRID = (NT * DM + 255) / 256;

  concat_kernel<<<ELEM_GRID, 256, 0, stream>>>(q_weight, x_tokens, x);

  for (int i = 0; i <= NBLK; ++i) {
    ln_kernel<<<NT, 256, 0, stream>>>(x, norm_g, norm_b, lnbuf);
    float* mask_i = out + (size_t)i * NQ * NPATCH;
    float* cls_i  = out + (size_t)5 * NQ * NPATCH + (size_t)i * NQ * NCLS;
    gemm_kernel<0, 1><<<ggrid(NQ, DM), 256, 0, stream>>>(lnbuf, mask_W1, mask_b1, f1, NQ, DM, DM);
    gemm_kernel<0, 1><<<ggrid(NQ, DM), 256, 0, stream>>>(f1, mask_W2, mask_b2, f2, NQ, DM, DM);
    gemm_kernel<0, 0><<<ggrid(NQ, DM), 256, 0, stream>>>(f2, mask_W3, mask_b3, f1, NQ, DM, DM);
    gemm_kernel<1, 0><<<ggrid(NQ, NPATCH), 256, 0, stream>>>(
        f1, lnbuf + (size_t)(NQ + PFX) * DM, nullptr, mask_i, NQ, NPATCH, DM);
    gemm_kernel<0, 0><<<ggrid(NQ, NCLS), 256, 0, stream>>>(lnbuf, class_W, class_b, cls_i, NQ, NCLS, DM);
    if (i == NBLK) break;

    ln_kernel<<<NT, 256, 0, stream>>>(x, ln1_g + i * DM, ln1_b + i * DM, lnbuf);
    gemm_kernel<0, 0><<<ggrid(NT, 3 * DM), 256, 0, stream>>>(
        lnbuf, qkv_W + (size_t)i * DM * 3 * DM, qkv_b + i * 3 * DM, big, NT, 3 * DM, DM);
    fattn_kernel<<<dim3(NKT, NHEAD), 256, 0, stream>>>(big, mask_i, attn_o);
    gemm_kernel<0, 0><<<ggrid(NT, DM), 256, 0, stream>>>(
        attn_o, proj_W + (size_t)i * DM * DM, proj_b + i * DM, tmp, NT, DM, DM);
    resid_kernel<<<ELEM_GRID, 256, 0, stream>>>(x, tmp, ls1 + i * DM);
    ln_kernel<<<NT, 256, 0, stream>>>(x, ln2_g + i * DM, ln2_b + i * DM, lnbuf);
    gemm_kernel<0, 1><<<ggrid(NT, 4 * DM), 256, 0, stream>>>(
        lnbuf, fc1_W + (size_t)i * DM * 4 * DM, fc1_b + i * 4 * DM, big, NT, 4 * DM, DM);
    gemm_kernel<0, 0><<<ggrid(NT, DM), 256, 0, stream>>>(
        big, fc2_W + (size_t)i * 4 * DM * DM, fc2_b + i * DM, tmp, NT, DM, 4 * DM);
    resid_kernel<<<ELEM_GRID, 256, 0, stream>>>(x, tmp, ls2 + i * DM);
  }
}

// Round 3
// 9396.593 us; speedup vs baseline: 2.7054x; 1.6050x over previous
//
#include <hip/hip_runtime.h>
#include <hip/hip_bf16.h>

#define NQ 200
#define PFX 5
#define NPATCH 1600
#define NT 1805
#define DM 1024
#define NHEAD 16
#define DHEAD 64
#define NBLK 4
#define NCLS 151
#define NKT 29     // ceil(1805/64)
#define NWRD 57    // ceil(1805/32) mask words per query row

__device__ __forceinline__ float gelu_f(float x) {
  return 0.5f * x * (1.0f + erff(x * 0.7071067811865476f));
}

// ---------------- concat: x = [q_weight ; x_tokens] ----------------
__global__ __launch_bounds__(256) void concat_kernel(const float* __restrict__ qw,
    const float* __restrict__ xt, float* __restrict__ x) {
  int idx = blockIdx.x * 256 + threadIdx.x;
  if (idx >= NT * DM) return;
  int n = idx >> 10;
  x[idx] = (n < NQ) ? qw[idx] : xt[idx - NQ * DM];
}

// ---------------- LayerNorm over D=1024, one block per row ----------------
__global__ __launch_bounds__(256) void ln_kernel(const float* __restrict__ in,
    const float* __restrict__ g, const float* __restrict__ b, float* __restrict__ out) {
  const int row = blockIdx.x;
  const int tid = threadIdx.x;
  const float* x = in + (size_t)row * DM;
  float v[4];
#pragma unroll
  for (int i = 0; i < 4; ++i) v[i] = x[tid + (i << 8)];
  float s = v[0] + v[1] + v[2] + v[3];
  __shared__ float red[4];
  __shared__ float red2[4];
#pragma unroll
  for (int off = 32; off; off >>= 1) s += __shfl_down(s, off, 64);
  if ((tid & 63) == 0) red[tid >> 6] = s;
  __syncthreads();
  float mean = (red[0] + red[1] + red[2] + red[3]) * (1.0f / DM);
  float sq = 0.f;
#pragma unroll
  for (int i = 0; i < 4; ++i) { float d = v[i] - mean; sq += d * d; }
#pragma unroll
  for (int off = 32; off; off >>= 1) sq += __shfl_down(sq, off, 64);
  if ((tid & 63) == 0) red2[tid >> 6] = sq;
  __syncthreads();
  float var = (red2[0] + red2[1] + red2[2] + red2[3]) * (1.0f / DM);
  float inv = 1.0f / sqrtf(var + 1e-6f);
  float* y = out + (size_t)row * DM;
#pragma unroll
  for (int i = 0; i < 4; ++i) {
    int d = tid + (i << 8);
    y[d] = (v[i] - mean) * inv * g[d] + b[d];
  }
}

// ---------------- generic fp32 GEMM: C = act(A@B + bias) ----------------
template <int TRANSB, int ACT>
__global__ __launch_bounds__(256) void gemm_kernel(const float* __restrict__ A,
    const float* __restrict__ B, const float* __restrict__ bias, float* __restrict__ C,
    int M, int Nc, int K) {
  __shared__ float As[16][68];
  __shared__ float Bs[16][68];
  const int bm = blockIdx.y * 64;
  const int bn = blockIdx.x * 64;
  const int tid = threadIdx.x;
  const int tm = (tid >> 4) << 2;
  const int tn = (tid & 15) << 2;
  float acc[4][4] = {};
  for (int k0 = 0; k0 < K; k0 += 16) {
#pragma unroll
    for (int i = 0; i < 4; ++i) {
      int e = tid + (i << 8);
      int r = e >> 4, kk = e & 15;
      int gm = bm + r;
      As[kk][r] = (gm < M) ? A[(size_t)gm * K + (k0 + kk)] : 0.f;
      if (TRANSB) {
        int gn = bn + r;
        Bs[kk][r] = (gn < Nc) ? B[(size_t)gn * K + (k0 + kk)] : 0.f;
      } else {
        int kk2 = e >> 6, n2 = e & 63;
        int gn = bn + n2;
        Bs[kk2][n2] = (gn < Nc) ? B[(size_t)(k0 + kk2) * Nc + gn] : 0.f;
      }
    }
    __syncthreads();
#pragma unroll
    for (int kk = 0; kk < 16; ++kk) {
      float a[4], b[4];
#pragma unroll
      for (int i = 0; i < 4; ++i) a[i] = As[kk][tm + i];
#pragma unroll
      for (int j = 0; j < 4; ++j) b[j] = Bs[kk][tn + j];
#pragma unroll
      for (int i = 0; i < 4; ++i)
#pragma unroll
        for (int j = 0; j < 4; ++j) acc[i][j] = fmaf(a[i], b[j], acc[i][j]);
    }
    __syncthreads();
  }
#pragma unroll
  for (int i = 0; i < 4; ++i) {
    int gm = bm + tm + i;
    if (gm >= M) continue;
#pragma unroll
    for (int j = 0; j < 4; ++j) {
      int gn = bn + tn + j;
      if (gn >= Nc) continue;
      float v = acc[i][j] + (bias ? bias[gn] : 0.f);
      if (ACT == 1) v = gelu_f(v);
      C[(size_t)gm * Nc + gn] = v;
    }
  }
}

// ---------------- pack attention keep-mask into bits ----------------
// bits[q][w] bit b == 1  =>  attention column c = 32w+b is KEPT for query row q.
// Columns < NQ+PFX always kept; patch columns kept iff mask logit > 0; c >= NT -> 0.
__global__ __launch_bounds__(256) void maskpack_kernel(const float* __restrict__ mlog,
    unsigned* __restrict__ bits) {
  int idx = blockIdx.x * 256 + threadIdx.x;
  if (idx >= NQ * NWRD) return;
  int q = idx / NWRD, w = idx - q * NWRD;
  unsigned word = 0u;
  int c0 = w * 32;
#pragma unroll
  for (int b = 0; b < 32; ++b) {
    int c = c0 + b;
    unsigned keep;
    if (c < NQ + PFX) keep = 1u;
    else if (c < NT) keep = (mlog[(size_t)q * NPATCH + (c - NQ - PFX)] > 0.f) ? 1u : 0u;
    else keep = 0u;
    word |= keep << b;
  }
  bits[idx] = word;
}

// ---------------- flash attention v2: block = (64-row q-tile, head) ----------------
// Register-pressure-disciplined: hold k[4]/v[4], stream q/p; packed bias bits.
__global__ __launch_bounds__(256) void fattn_kernel(const float* __restrict__ qkv,
    const unsigned* __restrict__ bits, float* __restrict__ o) {
  const int q0 = blockIdx.x * 64;
  const int h = blockIdx.y;
  const int tid = threadIdx.x;
  const int qg = tid >> 4;   // 0..15: owns q rows 4qg..4qg+3
  const int kg = tid & 15;   // 0..15: owns k cols 4kg..4kg+3 / out dims 4kg..4kg+3

  __shared__ float Qs[64][64];
  __shared__ float Ks[64][64];  // K tile; reused as P buffer
  __shared__ float Vs[64][64];
  __shared__ float rm[64], rl[64], rf[64];

#pragma unroll 2
  for (int ii = 0; ii < 4; ++ii) {
    int e = tid + (ii << 8);
    int r = e >> 4, bi = e & 15;
    int gq = q0 + r;
    float4 qv = make_float4(0.f, 0.f, 0.f, 0.f);
    if (gq < NT) qv = *(const float4*)(qkv + (size_t)gq * 3072 + h * 64 + bi * 4);
    *(float4*)&Qs[r][((bi ^ (r >> 2)) & 15) * 4] = qv;
  }
  if (tid < 64) { rm[tid] = -3.0e38f; rl[tid] = 0.f; }
  float o_acc[4][4] = {};

  for (int kt = 0; kt < NKT; ++kt) {
    __syncthreads();
#pragma unroll 2
    for (int ii = 0; ii < 4; ++ii) {
      int e = tid + (ii << 8);
      int r = e >> 4, bi = e & 15;
      int gk = kt * 64 + r;
      float4 kv = make_float4(0.f, 0.f, 0.f, 0.f), vv = kv;
      if (gk < NT) {
        kv = *(const float4*)(qkv + (size_t)gk * 3072 + 1024 + h * 64 + bi * 4);
        vv = *(const float4*)(qkv + (size_t)gk * 3072 + 2048 + h * 64 + bi * 4);
      }
      int sb = ((bi ^ (r >> 2)) & 15) * 4;
      *(float4*)&Ks[r][sb] = kv;
      *(float4*)&Vs[r][sb] = vv;
    }
    __syncthreads();

    // ---- phase A: scores ----
    float s[4][4] = {};
#pragma unroll 2
    for (int d4 = 0; d4 < 16; ++d4) {
      float4 k4r[4];
#pragma unroll
      for (int j = 0; j < 4; ++j) k4r[j] = *(const float4*)&Ks[kg * 4 + j][((d4 ^ kg) & 15) * 4];
#pragma unroll
      for (int i = 0; i < 4; ++i) {
        float4 q = *(const float4*)&Qs[qg * 4 + i][((d4 ^ qg) & 15) * 4];
#pragma unroll
        for (int j = 0; j < 4; ++j) {
          s[i][j] = fmaf(q.x, k4r[j].x, s[i][j]);
          s[i][j] = fmaf(q.y, k4r[j].y, s[i][j]);
          s[i][j] = fmaf(q.z, k4r[j].z, s[i][j]);
          s[i][j] = fmaf(q.w, k4r[j].w, s[i][j]);
        }
      }
    }
    // ---- scale + packed-bit bias + OOB ----
    const int lastTile = (kt == NKT - 1);
#pragma unroll
    for (int i = 0; i < 4; ++i) {
      int gq = q0 + qg * 4 + i;
      unsigned w = 0xFFFFFFFFu;
      if (gq < NQ) w = bits[gq * NWRD + kt * 2 + (kg >> 3)];
#pragma unroll
      for (int j = 0; j < 4; ++j) {
        float sv = s[i][j] * 0.125f;
        if (!((w >> (((kg & 7) << 2) + j)) & 1u)) sv -= 1e9f;
        if (lastTile && (kt * 64 + kg * 4 + j) >= NT) sv = -3.0e38f;
        s[i][j] = sv;
      }
    }

    // ---- phase B: online softmax ----
    float mnew[4], f[4], psum[4];
#pragma unroll
    for (int i = 0; i < 4; ++i) {
      float tm = fmaxf(fmaxf(s[i][0], s[i][1]), fmaxf(s[i][2], s[i][3]));
#pragma unroll
      for (int m2 = 1; m2 < 16; m2 <<= 1) tm = fmaxf(tm, __shfl_xor(tm, m2, 64));
      float rmold = rm[qg * 4 + i];
      mnew[i] = fmaxf(rmold, tm);
      f[i] = expf(rmold - mnew[i]);
      float ps = 0.f;
#pragma unroll
      for (int j = 0; j < 4; ++j) {
        s[i][j] = expf(s[i][j] - mnew[i]);
        ps += s[i][j];
      }
#pragma unroll
      for (int m2 = 1; m2 < 16; m2 <<= 1) ps += __shfl_xor(ps, m2, 64);
      psum[i] = ps;
    }
    __syncthreads();

#pragma unroll
    for (int i = 0; i < 4; ++i) {
      int r = qg * 4 + i;
      *(float4*)&Ks[r][((kg ^ qg) & 15) * 4] = make_float4(s[i][0], s[i][1], s[i][2], s[i][3]);
    }
    if (kg == 0) {
#pragma unroll
      for (int i = 0; i < 4; ++i) {
        int r = qg * 4 + i;
        rm[r] = mnew[i];
        rl[r] = rl[r] * f[i] + psum[i];
        rf[r] = f[i];
      }
    }
    __syncthreads();

    // ---- phase C: O = O*rf + P@V ----
#pragma unroll
    for (int i = 0; i < 4; ++i) {
      float fi = rf[qg * 4 + i];
#pragma unroll
      for (int c = 0; c < 4; ++c) o_acc[i][c] *= fi;
    }
#pragma unroll 2
    for (int k4 = 0; k4 < 16; ++k4) {
      float4 v4r[4];
#pragma unroll
      for (int j = 0; j < 4; ++j) v4r[j] = *(const float4*)&Vs[k4 * 4 + j][((kg ^ k4) & 15) * 4];
#pragma unroll
      for (int i = 0; i < 4; ++i) {
        float4 p = *(const float4*)&Ks[qg * 4 + i][((k4 ^ qg) & 15) * 4];
        const float* pp = (const float*)&p;
#pragma unroll
        for (int j = 0; j < 4; ++j) {
          o_acc[i][0] = fmaf(pp[j], v4r[j].x, o_acc[i][0]);
          o_acc[i][1] = fmaf(pp[j], v4r[j].y, o_acc[i][1]);
          o_acc[i][2] = fmaf(pp[j], v4r[j].z, o_acc[i][2]);
          o_acc[i][3] = fmaf(pp[j], v4r[j].w, o_acc[i][3]);
        }
      }
    }
  }

  // ---- epilogue ----
#pragma unroll
  for (int i = 0; i < 4; ++i) {
    int gq = q0 + qg * 4 + i;
    if (gq >= NT) continue;
    float inv = 1.0f / rl[qg * 4 + i];
    float4 ov = make_float4(o_acc[i][0] * inv, o_acc[i][1] * inv, o_acc[i][2] * inv, o_acc[i][3] * inv);
    *(float4*)(o + (size_t)gq * DM + h * 64 + kg * 4) = ov;
  }
}

// ---------------- residual with layer-scale: x += ls * y ----------------
__global__ __launch_bounds__(256) void resid_kernel(float* __restrict__ x,
    const float* __restrict__ y, const float* __restrict__ ls) {
  int idx = blockIdx.x * 256 + threadIdx.x;
  if (idx >= NT * DM) return;
  int d = idx & (DM - 1);
  x[idx] = fmaf(ls[d], y[idx], x[idx]);
}

extern "C" void kernel_launch(void* const* d_in, const int* in_sizes, int n_in,
                              void* d_out, int out_size, void* d_ws, size_t ws_size,
                              hipStream_t stream) {
  const float* x_tokens = (const float*)d_in[0];
  const float* q_weight = (const float*)d_in[1];
  const float* norm_g   = (const float*)d_in[2];
  const float* norm_b   = (const float*)d_in[3];
  const float* class_W  = (const float*)d_in[4];
  const float* class_b  = (const float*)d_in[5];
  const float* mask_W1  = (const float*)d_in[6];
  const float* mask_b1  = (const float*)d_in[7];
  const float* mask_W2  = (const float*)d_in[8];
  const float* mask_b2  = (const float*)d_in[9];
  const float* mask_W3  = (const float*)d_in[10];
  const float* mask_b3  = (const float*)d_in[11];
  const float* ln1_g    = (const float*)d_in[12];
  const float* ln1_b    = (const float*)d_in[13];
  const float* ln2_g    = (const float*)d_in[14];
  const float* ln2_b    = (const float*)d_in[15];
  const float* qkv_W    = (const float*)d_in[16];
  const float* qkv_b    = (const float*)d_in[17];
  const float* proj_W   = (const float*)d_in[18];
  const float* proj_b   = (const float*)d_in[19];
  const float* ls1      = (const float*)d_in[20];
  const float* ls2      = (const float*)d_in[21];
  const float* fc1_W    = (const float*)d_in[22];
  const float* fc1_b    = (const float*)d_in[23];
  const float* fc2_W    = (const float*)d_in[24];
  const float* fc2_b    = (const float*)d_in[25];

  float* out = (float*)d_out;
  float* ws = (float*)d_ws;
  float* x      = ws;
  float* lnbuf  = x + (size_t)NT * DM;
  float* attn_o = lnbuf + (size_t)NT * DM;
  float* tmp    = attn_o + (size_t)NT * DM;
  float* f1     = tmp + (size_t)NT * DM;
  float* f2     = f1 + (size_t)NQ * DM;
  float* big    = f2 + (size_t)NQ * DM;
  unsigned* bias_bits = (unsigned*)(big + (size_t)NT * 4 * DM);

  auto ggrid = [](int M, int Nc) { return dim3((Nc + 63) / 64, (M + 63) / 64); };
  const int ELEM_GRID = (NT * DM + 255) / 256;

  concat_kernel<<<ELEM_GRID, 256, 0, stream>>>(q_weight, x_tokens, x);

  for (int i = 0; i <= NBLK; ++i) {
    ln_kernel<<<NT, 256, 0, stream>>>(x, norm_g, norm_b, lnbuf);
    float* mask_i = out + (size_t)i * NQ * NPATCH;
    float* cls_i  = out + (size_t)5 * NQ * NPATCH + (size_t)i * NQ * NCLS;
    gemm_kernel<0, 1><<<ggrid(NQ, DM), 256, 0, stream>>>(lnbuf, mask_W1, mask_b1, f1, NQ, DM, DM);
    gemm_kernel<0, 1><<<ggrid(NQ, DM), 256, 0, stream>>>(f1, mask_W2, mask_b2, f2, NQ, DM, DM);
    gemm_kernel<0, 0><<<ggrid(NQ, DM), 256, 0, stream>>>(f2, mask_W3, mask_b3, f1, NQ, DM, DM);
    gemm_kernel<1, 0><<<ggrid(NQ, NPATCH), 256, 0, stream>>>(
        f1, lnbuf + (size_t)(NQ + PFX) * DM, nullptr, mask_i, NQ, NPATCH, DM);
    gemm_kernel<0, 0><<<ggrid(NQ, NCLS), 256, 0, stream>>>(lnbuf, class_W, class_b, cls_i, NQ, NCLS, DM);
    if (i == NBLK) break;

    ln_kernel<<<NT, 256, 0, stream>>>(x, ln1_g + i * DM, ln1_b + i * DM, lnbuf);
    gemm_kernel<0, 0><<<ggrid(NT, 3 * DM), 256, 0, stream>>>(
        lnbuf, qkv_W + (size_t)i * DM * 3 * DM, qkv_b + i * 3 * DM, big, NT, 3 * DM, DM);
    maskpack_kernel<<<(NQ * NWRD + 255) / 256, 256, 0, stream>>>(mask_i, bias_bits);
    fattn_kernel<<<dim3(NKT, NHEAD), 256, 0, stream>>>(big, bias_bits, attn_o);
    gemm_kernel<0, 0><<<ggrid(NT, DM), 256, 0, stream>>>(
        attn_o, proj_W + (size_t)i * DM * DM, proj_b + i * DM, tmp, NT, DM, DM);
    resid_kernel<<<ELEM_GRID, 256, 0, stream>>>(x, tmp, ls1 + i * DM);
    ln_kernel<<<NT, 256, 0, stream>>>(x, ln2_g + i * DM, ln2_b + i * DM, lnbuf);
    gemm_kernel<0, 1><<<ggrid(NT, 4 * DM), 256, 0, stream>>>(
        lnbuf, fc1_W + (size_t)i * DM * 4 * DM, fc1_b + i * 4 * DM, big, NT, 4 * DM, DM);
    gemm_kernel<0, 0><<<ggrid(NT, DM), 256, 0, stream>>>(
        big, fc2_W + (size_t)i * 4 * DM * DM, fc2_b + i * DM, tmp, NT, DM, 4 * DM);
    resid_kernel<<<ELEM_GRID, 256, 0, stream>>>(x, tmp, ls2 + i * DM);
  }
}

// Round 5
// 4058.838 us; speedup vs baseline: 6.2633x; 2.3151x over previous
//
#include <hip/hip_runtime.h>
#include <hip/hip_bf16.h>

#define NQ 200
#define PFX 5
#define NPATCH 1600
#define NT 1805
#define DM 1024
#define NHEAD 16
#define DHEAD 64
#define NBLK 4
#define NCLS 151
#define NKT 29     // ceil(1805/64)
#define NWRD 57    // ceil(1805/32) mask words per query row
#define LDSW 40    // shorts per LDS row (80B, 16B-aligned, swizzle-friendly)

typedef short s16x8 __attribute__((ext_vector_type(8)));
typedef float f32x4 __attribute__((ext_vector_type(4)));

__device__ __forceinline__ float gelu_f(float x) {
  return 0.5f * x * (1.0f + erff(x * 0.7071067811865476f));
}
__device__ __forceinline__ short f2bf(float x) {
  __hip_bfloat16 h = __float2bfloat16(x);
  return *reinterpret_cast<short*>(&h);
}
__device__ __forceinline__ float bf2f(short s) {
  __hip_bfloat16 h;
  *reinterpret_cast<short*>(&h) = s;
  return __bfloat162float(h);
}
// LDS addressing: row-major rows of LDSW shorts; 16B chunk XOR swizzle.
__device__ __forceinline__ int swz(int row, int chunk) {
  return row * LDSW + (((chunk ^ ((row >> 3) & 3)) << 3));
}

// ---------------- concat: x = [q_weight ; x_tokens] ----------------
__global__ __launch_bounds__(256) void concat_kernel(const float* __restrict__ qw,
    const float* __restrict__ xt, float* __restrict__ x) {
  int idx = blockIdx.x * 256 + threadIdx.x;
  if (idx >= NT * DM) return;
  int n = idx >> 10;
  x[idx] = (n < NQ) ? qw[idx] : xt[idx - NQ * DM];
}

// ---------------- LayerNorm -> bf16 hi/lo ----------------
__global__ __launch_bounds__(256) void ln_kernel(const float* __restrict__ in,
    const float* __restrict__ g, const float* __restrict__ b,
    short* __restrict__ oh, short* __restrict__ ol) {
  const int row = blockIdx.x;
  const int tid = threadIdx.x;
  const float* x = in + (size_t)row * DM;
  float v[4];
#pragma unroll
  for (int i = 0; i < 4; ++i) v[i] = x[tid + (i << 8)];
  float s = v[0] + v[1] + v[2] + v[3];
  __shared__ float red[4];
  __shared__ float red2[4];
#pragma unroll
  for (int off = 32; off; off >>= 1) s += __shfl_down(s, off, 64);
  if ((tid & 63) == 0) red[tid >> 6] = s;
  __syncthreads();
  float mean = (red[0] + red[1] + red[2] + red[3]) * (1.0f / DM);
  float sq = 0.f;
#pragma unroll
  for (int i = 0; i < 4; ++i) { float d = v[i] - mean; sq += d * d; }
#pragma unroll
  for (int off = 32; off; off >>= 1) sq += __shfl_down(sq, off, 64);
  if ((tid & 63) == 0) red2[tid >> 6] = sq;
  __syncthreads();
  float var = (red2[0] + red2[1] + red2[2] + red2[3]) * (1.0f / DM);
  float inv = 1.0f / sqrtf(var + 1e-6f);
#pragma unroll
  for (int i = 0; i < 4; ++i) {
    int d = tid + (i << 8);
    float y = (v[i] - mean) * inv * g[d] + b[d];
    short hh = f2bf(y);
    oh[(size_t)row * DM + d] = hh;
    ol[(size_t)row * DM + d] = f2bf(y - bf2f(hh));
  }
}

// ---------------- bf16x3 MFMA GEMM, on-the-fly weight conversion ----------------
// A: bf16 hi/lo, M x K row-major (pre-split activations).
// B: BSRC==0: fp32 K x N row-major (original weights; transpose+split in staging)
//    BSRC==1: bf16 hi/lo, N x K row-major (pre-split, "transposed" activations)
// C = act(A@B + bias). 128x128 tile, BK=32, 4 waves (2x2), 64x64 per wave.
template <int BSRC, int ACT, int WF32, int WBF16>
__global__ __launch_bounds__(256, 2) void mgemm_kernel(
    const short* __restrict__ Ah, const short* __restrict__ Al,
    const float* __restrict__ Wf,
    const short* __restrict__ Bh, const short* __restrict__ Bl,
    const float* __restrict__ bias,
    float* __restrict__ Cf, short* __restrict__ Ch, short* __restrict__ Cl,
    int M, int N, int K) {
  __shared__ __align__(16) short sAh[128 * LDSW], sAl[128 * LDSW];
  __shared__ __align__(16) short sBh[128 * LDSW], sBl[128 * LDSW];
  const int tid = threadIdx.x;
  const int lane = tid & 63;
  const int wave = tid >> 6;
  const int wm = (wave >> 1) << 6;
  const int wn = (wave & 1) << 6;
  const int bm = blockIdx.y << 7;
  const int bn = blockIdx.x << 7;

  // A staging geometry: thread -> (row, chunk-pair)
  const int sr = tid >> 1;             // 0..127
  const int sc = (tid & 1) << 1;       // chunk 0 or 2
  const size_t aoff = (size_t)min(bm + sr, M - 1) * K + (sc << 3);

  f32x4 acc[4][4];
  {
    f32x4 z = {0.f, 0.f, 0.f, 0.f};
#pragma unroll
    for (int mi = 0; mi < 4; ++mi)
#pragma unroll
      for (int ni = 0; ni < 4; ++ni) acc[mi][ni] = z;
  }

  // prefetch registers
  uint4 pAh0, pAh1, pAl0, pAl1;
  uint4 pBh0, pBh1, pBl0, pBl1;
  float wB[4][4];
  size_t boff = 0;

  auto loadA = [&](int k0) {
    pAh0 = *(const uint4*)(Ah + aoff + k0);
    pAh1 = *(const uint4*)(Ah + aoff + k0 + 8);
    pAl0 = *(const uint4*)(Al + aoff + k0);
    pAl1 = *(const uint4*)(Al + aoff + k0 + 8);
  };
  auto loadB = [&](int k0) {
    if (BSRC == 1) {
      pBh0 = *(const uint4*)(Bh + boff + k0);
      pBh1 = *(const uint4*)(Bh + boff + k0 + 8);
      pBl0 = *(const uint4*)(Bl + boff + k0);
      pBl1 = *(const uint4*)(Bl + boff + k0 + 8);
    } else {
#pragma unroll
      for (int p2 = 0; p2 < 4; ++p2) {
        int n = (tid & 63) + ((p2 & 1) << 6);
        int kq = (tid >> 6) + ((p2 >> 1) << 2);
        int gn = min(bn + n, N - 1);
        const float* Wp = Wf + (size_t)(k0 + (kq << 2)) * N + gn;
#pragma unroll
        for (int r2 = 0; r2 < 4; ++r2) wB[p2][r2] = Wp[(size_t)r2 * N];
      }
    }
  };

  if (BSRC == 1) boff = (size_t)min(bn + sr, N - 1) * K + (sc << 3);
  loadA(0);
  loadB(0);

  for (int k0 = 0; k0 < K; k0 += 32) {
    __syncthreads();  // previous MFMA phase done with LDS
    // ---- write staged tile ----
    *(uint4*)&sAh[swz(sr, sc)] = pAh0;
    *(uint4*)&sAh[swz(sr, sc + 1)] = pAh1;
    *(uint4*)&sAl[swz(sr, sc)] = pAl0;
    *(uint4*)&sAl[swz(sr, sc + 1)] = pAl1;
    if (BSRC == 1) {
      *(uint4*)&sBh[swz(sr, sc)] = pBh0;
      *(uint4*)&sBh[swz(sr, sc + 1)] = pBh1;
      *(uint4*)&sBl[swz(sr, sc)] = pBl0;
      *(uint4*)&sBl[swz(sr, sc + 1)] = pBl1;
    } else {
#pragma unroll
      for (int p2 = 0; p2 < 4; ++p2) {
        int n = (tid & 63) + ((p2 & 1) << 6);
        int kq = (tid >> 6) + ((p2 >> 1) << 2);
        short h0 = f2bf(wB[p2][0]), h1 = f2bf(wB[p2][1]);
        short h2 = f2bf(wB[p2][2]), h3 = f2bf(wB[p2][3]);
        short l0 = f2bf(wB[p2][0] - bf2f(h0)), l1 = f2bf(wB[p2][1] - bf2f(h1));
        short l2 = f2bf(wB[p2][2] - bf2f(h2)), l3 = f2bf(wB[p2][3] - bf2f(h3));
        int off = n * LDSW + ((((kq >> 1) ^ ((n >> 3) & 3)) << 3) + ((kq & 1) << 2));
        *(short4*)&sBh[off] = make_short4(h0, h1, h2, h3);
        *(short4*)&sBl[off] = make_short4(l0, l1, l2, l3);
      }
    }
    __syncthreads();
    if (k0 + 32 < K) {  // issue next-tile global loads; in flight during MFMA
      loadA(k0 + 32);
      loadB(k0 + 32);
    }
    // ---- fragments + MFMA ----
    const int ar = lane & 15;
    const int kc = lane >> 4;
    s16x8 fah[4], fal[4], fbh[4], fbl[4];
#pragma unroll
    for (int t2 = 0; t2 < 4; ++t2) {
      fah[t2] = *(const s16x8*)&sAh[swz(wm + (t2 << 4) + ar, kc)];
      fal[t2] = *(const s16x8*)&sAl[swz(wm + (t2 << 4) + ar, kc)];
      fbh[t2] = *(const s16x8*)&sBh[swz(wn + (t2 << 4) + ar, kc)];
      fbl[t2] = *(const s16x8*)&sBl[swz(wn + (t2 << 4) + ar, kc)];
    }
#pragma unroll
    for (int mi = 0; mi < 4; ++mi)
#pragma unroll
      for (int ni = 0; ni < 4; ++ni) {
        acc[mi][ni] = __builtin_amdgcn_mfma_f32_16x16x32_bf16(fah[mi], fbh[ni], acc[mi][ni], 0, 0, 0);
        acc[mi][ni] = __builtin_amdgcn_mfma_f32_16x16x32_bf16(fah[mi], fbl[ni], acc[mi][ni], 0, 0, 0);
        acc[mi][ni] = __builtin_amdgcn_mfma_f32_16x16x32_bf16(fal[mi], fbh[ni], acc[mi][ni], 0, 0, 0);
      }
  }

  // ---- epilogue: row = bm+wm+mi*16+(lane>>4)*4+rr, col = bn+wn+ni*16+(lane&15) ----
  const int erow = bm + wm + ((lane >> 4) << 2);
  const int ecol = bn + wn + (lane & 15);
  float bv[4];
#pragma unroll
  for (int ni = 0; ni < 4; ++ni) {
    int col = ecol + ni * 16;
    bv[ni] = (bias != nullptr && col < N) ? bias[col] : 0.f;
  }
#pragma unroll
  for (int mi = 0; mi < 4; ++mi) {
#pragma unroll
    for (int rr = 0; rr < 4; ++rr) {
      int row = erow + mi * 16 + rr;
      if (row >= M) continue;
#pragma unroll
      for (int ni = 0; ni < 4; ++ni) {
        int col = ecol + ni * 16;
        if (col >= N) continue;
        float v = acc[mi][ni][rr] + bv[ni];
        if (ACT == 1) v = gelu_f(v);
        size_t o = (size_t)row * N + col;
        if (WF32) Cf[o] = v;
        if (WBF16) {
          short hh = f2bf(v);
          Ch[o] = hh;
          Cl[o] = f2bf(v - bf2f(hh));
        }
      }
    }
  }
}

// ---------------- pack attention keep-mask into bits ----------------
__global__ __launch_bounds__(256) void maskpack_kernel(const float* __restrict__ mlog,
    unsigned* __restrict__ bits) {
  int idx = blockIdx.x * 256 + threadIdx.x;
  if (idx >= NQ * NWRD) return;
  int q = idx / NWRD, w = idx - q * NWRD;
  unsigned word = 0u;
  int c0 = w * 32;
#pragma unroll
  for (int b = 0; b < 32; ++b) {
    int c = c0 + b;
    unsigned keep;
    if (c < NQ + PFX) keep = 1u;
    else if (c < NT) keep = (mlog[(size_t)q * NPATCH + (c - NQ - PFX)] > 0.f) ? 1u : 0u;
    else keep = 0u;
    word |= keep << b;
  }
  bits[idx] = word;
}

// ---------------- flash attention: fp32 math, bf16 hi/lo output ----------------
__global__ __launch_bounds__(256) void fattn_kernel(const float* __restrict__ qkv,
    const unsigned* __restrict__ bits, short* __restrict__ ao_h, short* __restrict__ ao_l) {
  const int q0 = blockIdx.x * 64;
  const int h = blockIdx.y;
  const int tid = threadIdx.x;
  const int qg = tid >> 4;
  const int kg = tid & 15;

  __shared__ float Qs[64][64];
  __shared__ float Ks[64][64];
  __shared__ float Vs[64][64];
  __shared__ float rm[64], rl[64], rf[64];

#pragma unroll 2
  for (int ii = 0; ii < 4; ++ii) {
    int e = tid + (ii << 8);
    int r = e >> 4, bi = e & 15;
    int gq = q0 + r;
    float4 qv = make_float4(0.f, 0.f, 0.f, 0.f);
    if (gq < NT) qv = *(const float4*)(qkv + (size_t)gq * 3072 + h * 64 + bi * 4);
    *(float4*)&Qs[r][((bi ^ (r >> 2)) & 15) * 4] = qv;
  }
  if (tid < 64) { rm[tid] = -3.0e38f; rl[tid] = 0.f; }
  float o_acc[4][4] = {};

  for (int kt = 0; kt < NKT; ++kt) {
    __syncthreads();
#pragma unroll 2
    for (int ii = 0; ii < 4; ++ii) {
      int e = tid + (ii << 8);
      int r = e >> 4, bi = e & 15;
      int gk = kt * 64 + r;
      float4 kv = make_float4(0.f, 0.f, 0.f, 0.f), vv = kv;
      if (gk < NT) {
        kv = *(const float4*)(qkv + (size_t)gk * 3072 + 1024 + h * 64 + bi * 4);
        vv = *(const float4*)(qkv + (size_t)gk * 3072 + 2048 + h * 64 + bi * 4);
      }
      int sb = ((bi ^ (r >> 2)) & 15) * 4;
      *(float4*)&Ks[r][sb] = kv;
      *(float4*)&Vs[r][sb] = vv;
    }
    __syncthreads();

    float s[4][4] = {};
#pragma unroll 2
    for (int d4 = 0; d4 < 16; ++d4) {
      float4 k4r[4];
#pragma unroll
      for (int j = 0; j < 4; ++j) k4r[j] = *(const float4*)&Ks[kg * 4 + j][((d4 ^ kg) & 15) * 4];
#pragma unroll
      for (int i = 0; i < 4; ++i) {
        float4 q = *(const float4*)&Qs[qg * 4 + i][((d4 ^ qg) & 15) * 4];
#pragma unroll
        for (int j = 0; j < 4; ++j) {
          s[i][j] = fmaf(q.x, k4r[j].x, s[i][j]);
          s[i][j] = fmaf(q.y, k4r[j].y, s[i][j]);
          s[i][j] = fmaf(q.z, k4r[j].z, s[i][j]);
          s[i][j] = fmaf(q.w, k4r[j].w, s[i][j]);
        }
      }
    }
    const int lastTile = (kt == NKT - 1);
#pragma unroll
    for (int i = 0; i < 4; ++i) {
      int gq = q0 + qg * 4 + i;
      unsigned w = 0xFFFFFFFFu;
      if (gq < NQ) {
        int wi = kt * 2 + (kg >> 3);
        w = (wi < NWRD) ? bits[gq * NWRD + wi] : 0u;
      }
#pragma unroll
      for (int j = 0; j < 4; ++j) {
        float sv = s[i][j] * 0.125f;
        if (!((w >> (((kg & 7) << 2) + j)) & 1u)) sv -= 1e9f;
        if (lastTile && (kt * 64 + kg * 4 + j) >= NT) sv = -3.0e38f;
        s[i][j] = sv;
      }
    }

    float mnew[4], f[4], psum[4];
#pragma unroll
    for (int i = 0; i < 4; ++i) {
      float tm = fmaxf(fmaxf(s[i][0], s[i][1]), fmaxf(s[i][2], s[i][3]));
#pragma unroll
      for (int m2 = 1; m2 < 16; m2 <<= 1) tm = fmaxf(tm, __shfl_xor(tm, m2, 64));
      float rmold = rm[qg * 4 + i];
      mnew[i] = fmaxf(rmold, tm);
      f[i] = expf(rmold - mnew[i]);
      float ps = 0.f;
#pragma unroll
      for (int j = 0; j < 4; ++j) {
        s[i][j] = expf(s[i][j] - mnew[i]);
        ps += s[i][j];
      }
#pragma unroll
      for (int m2 = 1; m2 < 16; m2 <<= 1) ps += __shfl_xor(ps, m2, 64);
      psum[i] = ps;
    }
    __syncthreads();

#pragma unroll
    for (int i = 0; i < 4; ++i) {
      int r = qg * 4 + i;
      *(float4*)&Ks[r][((kg ^ qg) & 15) * 4] = make_float4(s[i][0], s[i][1], s[i][2], s[i][3]);
    }
    if (kg == 0) {
#pragma unroll
      for (int i = 0; i < 4; ++i) {
        int r = qg * 4 + i;
        rm[r] = mnew[i];
        rl[r] = rl[r] * f[i] + psum[i];
        rf[r] = f[i];
      }
    }
    __syncthreads();

#pragma unroll
    for (int i = 0; i < 4; ++i) {
      float fi = rf[qg * 4 + i];
#pragma unroll
      for (int c = 0; c < 4; ++c) o_acc[i][c] *= fi;
    }
#pragma unroll 2
    for (int k4 = 0; k4 < 16; ++k4) {
      float4 v4r[4];
#pragma unroll
      for (int j = 0; j < 4; ++j) v4r[j] = *(const float4*)&Vs[k4 * 4 + j][((kg ^ k4) & 15) * 4];
#pragma unroll
      for (int i = 0; i < 4; ++i) {
        float4 p = *(const float4*)&Ks[qg * 4 + i][((k4 ^ qg) & 15) * 4];
        const float* pp = (const float*)&p;
#pragma unroll
        for (int j = 0; j < 4; ++j) {
          o_acc[i][0] = fmaf(pp[j], v4r[j].x, o_acc[i][0]);
          o_acc[i][1] = fmaf(pp[j], v4r[j].y, o_acc[i][1]);
          o_acc[i][2] = fmaf(pp[j], v4r[j].z, o_acc[i][2]);
          o_acc[i][3] = fmaf(pp[j], v4r[j].w, o_acc[i][3]);
        }
      }
    }
  }

#pragma unroll
  for (int i = 0; i < 4; ++i) {
    int gq = q0 + qg * 4 + i;
    if (gq >= NT) continue;
    float inv = 1.0f / rl[qg * 4 + i];
    short hh[4], ll[4];
#pragma unroll
    for (int c = 0; c < 4; ++c) {
      float v = o_acc[i][c] * inv;
      hh[c] = f2bf(v);
      ll[c] = f2bf(v - bf2f(hh[c]));
    }
    size_t o = (size_t)gq * DM + h * 64 + kg * 4;
    *(short4*)(ao_h + o) = make_short4(hh[0], hh[1], hh[2], hh[3]);
    *(short4*)(ao_l + o) = make_short4(ll[0], ll[1], ll[2], ll[3]);
  }
}

// ---------------- residual with layer-scale: x += ls * y ----------------
__global__ __launch_bounds__(256) void resid_kernel(float* __restrict__ x,
    const float* __restrict__ y, const float* __restrict__ ls) {
  int idx = blockIdx.x * 256 + threadIdx.x;
  if (idx >= NT * DM) return;
  int d = idx & (DM - 1);
  x[idx] = fmaf(ls[d], y[idx], x[idx]);
}

extern "C" void kernel_launch(void* const* d_in, const int* in_sizes, int n_in,
                              void* d_out, int out_size, void* d_ws, size_t ws_size,
                              hipStream_t stream) {
  const float* x_tokens = (const float*)d_in[0];
  const float* q_weight = (const float*)d_in[1];
  const float* norm_g   = (const float*)d_in[2];
  const float* norm_b   = (const float*)d_in[3];
  const float* class_W  = (const float*)d_in[4];
  const float* class_b  = (const float*)d_in[5];
  const float* mask_W1  = (const float*)d_in[6];
  const float* mask_b1  = (const float*)d_in[7];
  const float* mask_W2  = (const float*)d_in[8];
  const float* mask_b2  = (const float*)d_in[9];
  const float* mask_W3  = (const float*)d_in[10];
  const float* mask_b3  = (const float*)d_in[11];
  const float* ln1_g    = (const float*)d_in[12];
  const float* ln1_b    = (const float*)d_in[13];
  const float* ln2_g    = (const float*)d_in[14];
  const float* ln2_b    = (const float*)d_in[15];
  const float* qkv_W    = (const float*)d_in[16];
  const float* qkv_b    = (const float*)d_in[17];
  const float* proj_W   = (const float*)d_in[18];
  const float* proj_b   = (const float*)d_in[19];
  const float* ls1      = (const float*)d_in[20];
  const float* ls2      = (const float*)d_in[21];
  const float* fc1_W    = (const float*)d_in[22];
  const float* fc1_b    = (const float*)d_in[23];
  const float* fc2_W    = (const float*)d_in[24];
  const float* fc2_b    = (const float*)d_in[25];

  float* out = (float*)d_out;

  // ---- workspace carve: total ~51.8 MB (proven ws_size >= 60.8 MB from round 2) ----
  char* p = (char*)d_ws;
  auto alloc = [&](size_t bytes) {
    char* r = p;
    p += (bytes + 255) & ~(size_t)255;
    return r;
  };
  float* x      = (float*)alloc((size_t)NT * DM * 4);      // 7.39 MB
  short* lnb_h  = (short*)alloc((size_t)NT * DM * 2);      // 3.70
  short* lnb_l  = (short*)alloc((size_t)NT * DM * 2);      // 3.70
  short* ao_h   = (short*)alloc((size_t)NT * DM * 2);      // 3.70 } fc2 fp32 out aliases
  short* ao_l   = (short*)alloc((size_t)NT * DM * 2);      // 3.70 } these two exactly
  float* tmp    = (float*)alloc((size_t)NT * DM * 4);      // 7.39 } g1 (bf16 h+l) aliases
  float* qkvbuf = (float*)alloc((size_t)NT * 3 * DM * 4);  // 22.18} tmp+qkvbuf exactly
  unsigned* bias_bits = (unsigned*)alloc((size_t)NQ * NWRD * 4);
  float* fc2o = (float*)ao_h;                  // NT*DM fp32 == ao_h+ao_l region
  short* g1_h = (short*)tmp;                   // NT*4*DM shorts
  short* g1_l = g1_h + (size_t)NT * 4 * DM;    // NT*4*DM shorts (ends exactly at qkvbuf end)
  short* f1_h = (short*)qkvbuf;                // predict scratch inside dead qkvbuf
  short* f1_l = f1_h + (size_t)NQ * DM;
  short* f2_h = f1_l + (size_t)NQ * DM;
  short* f2_l = f2_h + (size_t)NQ * DM;
  short* f3_h = f2_l + (size_t)NQ * DM;
  short* f3_l = f3_h + (size_t)NQ * DM;

  const int ELEM_GRID = (NT * DM + 255) / 256;
  auto ggrid = [](int M, int Nc) { return dim3((Nc + 127) / 128, (M + 127) / 128); };

  concat_kernel<<<ELEM_GRID, 256, 0, stream>>>(q_weight, x_tokens, x);

  for (int i = 0; i <= NBLK; ++i) {
    // ---- predict head on shared-norm LN(x) ----
    ln_kernel<<<NT, 256, 0, stream>>>(x, norm_g, norm_b, lnb_h, lnb_l);
    float* mask_i = out + (size_t)i * NQ * NPATCH;
    float* cls_i  = out + (size_t)5 * NQ * NPATCH + (size_t)i * NQ * NCLS;
    mgemm_kernel<0, 1, 0, 1><<<ggrid(NQ, DM), 256, 0, stream>>>(
        lnb_h, lnb_l, mask_W1, nullptr, nullptr, mask_b1, nullptr, f1_h, f1_l, NQ, DM, DM);
    mgemm_kernel<0, 1, 0, 1><<<ggrid(NQ, DM), 256, 0, stream>>>(
        f1_h, f1_l, mask_W2, nullptr, nullptr, mask_b2, nullptr, f2_h, f2_l, NQ, DM, DM);
    mgemm_kernel<0, 0, 0, 1><<<ggrid(NQ, DM), 256, 0, stream>>>(
        f2_h, f2_l, mask_W3, nullptr, nullptr, mask_b3, nullptr, f3_h, f3_l, NQ, DM, DM);
    mgemm_kernel<1, 0, 1, 0><<<ggrid(NQ, NPATCH), 256, 0, stream>>>(
        f3_h, f3_l, nullptr, lnb_h + (size_t)(NQ + PFX) * DM, lnb_l + (size_t)(NQ + PFX) * DM,
        nullptr, mask_i, nullptr, nullptr, NQ, NPATCH, DM);
    mgemm_kernel<0, 0, 1, 0><<<ggrid(NQ, NCLS), 256, 0, stream>>>(
        lnb_h, lnb_l, class_W, nullptr, nullptr, class_b, cls_i, nullptr, nullptr, NQ, NCLS, DM);
    if (i == NBLK) break;

    // ---- transformer block i ----
    ln_kernel<<<NT, 256, 0, stream>>>(x, ln1_g + i * DM, ln1_b + i * DM, lnb_h, lnb_l);
    mgemm_kernel<0, 0, 1, 0><<<ggrid(NT, 3 * DM), 256, 0, stream>>>(
        lnb_h, lnb_l, qkv_W + (size_t)i * DM * 3 * DM, nullptr, nullptr,
        qkv_b + i * 3 * DM, qkvbuf, nullptr, nullptr, NT, 3 * DM, DM);
    maskpack_kernel<<<(NQ * NWRD + 255) / 256, 256, 0, stream>>>(mask_i, bias_bits);
    fattn_kernel<<<dim3(NKT, NHEAD), 256, 0, stream>>>(qkvbuf, bias_bits, ao_h, ao_l);
    mgemm_kernel<0, 0, 1, 0><<<ggrid(NT, DM), 256, 0, stream>>>(
        ao_h, ao_l, proj_W + (size_t)i * DM * DM, nullptr, nullptr,
        proj_b + i * DM, tmp, nullptr, nullptr, NT, DM, DM);
    resid_kernel<<<ELEM_GRID, 256, 0, stream>>>(x, tmp, ls1 + i * DM);
    ln_kernel<<<NT, 256, 0, stream>>>(x, ln2_g + i * DM, ln2_b + i * DM, lnb_h, lnb_l);
    mgemm_kernel<0, 1, 0, 1><<<ggrid(NT, 4 * DM), 256, 0, stream>>>(
        lnb_h, lnb_l, fc1_W + (size_t)i * DM * 4 * DM, nullptr, nullptr,
        fc1_b + i * 4 * DM, nullptr, g1_h, g1_l, NT, 4 * DM, DM);
    mgemm_kernel<0, 0, 1, 0><<<ggrid(NT, DM), 256, 0, stream>>>(
        g1_h, g1_l, fc2_W + (size_t)i * 4 * DM * DM, nullptr, nullptr,
        fc2_b + i * DM, fc2o, nullptr, nullptr, NT, DM, 4 * DM);
    resid_kernel<<<ELEM_GRID, 256, 0, stream>>>(x, fc2o, ls2 + i * DM);
  }
}

// Round 6
// 3298.659 us; speedup vs baseline: 7.7067x; 1.2305x over previous
//
#include <hip/hip_runtime.h>
#include <hip/hip_bf16.h>

#define NQ 200
#define PFX 5
#define NPATCH 1600
#define NT 1805
#define DM 1024
#define NHEAD 16
#define DHEAD 64
#define NBLK 4
#define NCLS 151
#define NKT 29     // ceil(1805/64)
#define NWRD 57    // ceil(1805/32) mask words per query row
#define LDSW 40    // shorts per LDS row in mgemm (80B, 16B-aligned)

typedef short s16x8 __attribute__((ext_vector_type(8)));
typedef float f32x4 __attribute__((ext_vector_type(4)));

__device__ __forceinline__ float gelu_f(float x) {
  return 0.5f * x * (1.0f + erff(x * 0.7071067811865476f));
}
__device__ __forceinline__ short f2bf(float x) {
  __hip_bfloat16 h = __float2bfloat16(x);
  return *reinterpret_cast<short*>(&h);
}
__device__ __forceinline__ float bf2f(short s) {
  __hip_bfloat16 h;
  *reinterpret_cast<short*>(&h) = s;
  return __bfloat162float(h);
}
__device__ __forceinline__ int swz(int row, int chunk) {
  return row * LDSW + (((chunk ^ ((row >> 3) & 3)) << 3));
}

// ---------------- concat: x = [q_weight ; x_tokens] ----------------
__global__ __launch_bounds__(256) void concat_kernel(const float* __restrict__ qw,
    const float* __restrict__ xt, float* __restrict__ x) {
  int idx = blockIdx.x * 256 + threadIdx.x;
  if (idx >= NT * DM) return;
  int n = idx >> 10;
  x[idx] = (n < NQ) ? qw[idx] : xt[idx - NQ * DM];
}

// ---------------- LayerNorm -> bf16 hi/lo ----------------
__global__ __launch_bounds__(256) void ln_kernel(const float* __restrict__ in,
    const float* __restrict__ g, const float* __restrict__ b,
    short* __restrict__ oh, short* __restrict__ ol) {
  const int row = blockIdx.x;
  const int tid = threadIdx.x;
  const float* x = in + (size_t)row * DM;
  float v[4];
#pragma unroll
  for (int i = 0; i < 4; ++i) v[i] = x[tid + (i << 8)];
  float s = v[0] + v[1] + v[2] + v[3];
  __shared__ float red[4];
  __shared__ float red2[4];
#pragma unroll
  for (int off = 32; off; off >>= 1) s += __shfl_down(s, off, 64);
  if ((tid & 63) == 0) red[tid >> 6] = s;
  __syncthreads();
  float mean = (red[0] + red[1] + red[2] + red[3]) * (1.0f / DM);
  float sq = 0.f;
#pragma unroll
  for (int i = 0; i < 4; ++i) { float d = v[i] - mean; sq += d * d; }
#pragma unroll
  for (int off = 32; off; off >>= 1) sq += __shfl_down(sq, off, 64);
  if ((tid & 63) == 0) red2[tid >> 6] = sq;
  __syncthreads();
  float var = (red2[0] + red2[1] + red2[2] + red2[3]) * (1.0f / DM);
  float inv = 1.0f / sqrtf(var + 1e-6f);
#pragma unroll
  for (int i = 0; i < 4; ++i) {
    int d = tid + (i << 8);
    float y = (v[i] - mean) * inv * g[d] + b[d];
    short hh = f2bf(y);
    oh[(size_t)row * DM + d] = hh;
    ol[(size_t)row * DM + d] = f2bf(y - bf2f(hh));
  }
}

// ---------------- bf16x3 MFMA GEMM, on-the-fly weight conversion ----------------
template <int BSRC, int ACT, int WF32, int WBF16>
__global__ __launch_bounds__(256, 2) void mgemm_kernel(
    const short* __restrict__ Ah, const short* __restrict__ Al,
    const float* __restrict__ Wf,
    const short* __restrict__ Bh, const short* __restrict__ Bl,
    const float* __restrict__ bias,
    float* __restrict__ Cf, short* __restrict__ Ch, short* __restrict__ Cl,
    int M, int N, int K) {
  __shared__ __align__(16) short sAh[128 * LDSW], sAl[128 * LDSW];
  __shared__ __align__(16) short sBh[128 * LDSW], sBl[128 * LDSW];
  const int tid = threadIdx.x;
  const int lane = tid & 63;
  const int wave = tid >> 6;
  const int wm = (wave >> 1) << 6;
  const int wn = (wave & 1) << 6;
  const int bm = blockIdx.y << 7;
  const int bn = blockIdx.x << 7;

  const int sr = tid >> 1;
  const int sc = (tid & 1) << 1;
  const size_t aoff = (size_t)min(bm + sr, M - 1) * K + (sc << 3);

  f32x4 acc[4][4];
  {
    f32x4 z = {0.f, 0.f, 0.f, 0.f};
#pragma unroll
    for (int mi = 0; mi < 4; ++mi)
#pragma unroll
      for (int ni = 0; ni < 4; ++ni) acc[mi][ni] = z;
  }

  uint4 pAh0, pAh1, pAl0, pAl1;
  uint4 pBh0, pBh1, pBl0, pBl1;
  float wB[4][4];
  size_t boff = 0;

  auto loadA = [&](int k0) {
    pAh0 = *(const uint4*)(Ah + aoff + k0);
    pAh1 = *(const uint4*)(Ah + aoff + k0 + 8);
    pAl0 = *(const uint4*)(Al + aoff + k0);
    pAl1 = *(const uint4*)(Al + aoff + k0 + 8);
  };
  auto loadB = [&](int k0) {
    if (BSRC == 1) {
      pBh0 = *(const uint4*)(Bh + boff + k0);
      pBh1 = *(const uint4*)(Bh + boff + k0 + 8);
      pBl0 = *(const uint4*)(Bl + boff + k0);
      pBl1 = *(const uint4*)(Bl + boff + k0 + 8);
    } else {
#pragma unroll
      for (int p2 = 0; p2 < 4; ++p2) {
        int n = (tid & 63) + ((p2 & 1) << 6);
        int kq = (tid >> 6) + ((p2 >> 1) << 2);
        int gn = min(bn + n, N - 1);
        const float* Wp = Wf + (size_t)(k0 + (kq << 2)) * N + gn;
#pragma unroll
        for (int r2 = 0; r2 < 4; ++r2) wB[p2][r2] = Wp[(size_t)r2 * N];
      }
    }
  };

  if (BSRC == 1) boff = (size_t)min(bn + sr, N - 1) * K + (sc << 3);
  loadA(0);
  loadB(0);

  for (int k0 = 0; k0 < K; k0 += 32) {
    __syncthreads();
    *(uint4*)&sAh[swz(sr, sc)] = pAh0;
    *(uint4*)&sAh[swz(sr, sc + 1)] = pAh1;
    *(uint4*)&sAl[swz(sr, sc)] = pAl0;
    *(uint4*)&sAl[swz(sr, sc + 1)] = pAl1;
    if (BSRC == 1) {
      *(uint4*)&sBh[swz(sr, sc)] = pBh0;
      *(uint4*)&sBh[swz(sr, sc + 1)] = pBh1;
      *(uint4*)&sBl[swz(sr, sc)] = pBl0;
      *(uint4*)&sBl[swz(sr, sc + 1)] = pBl1;
    } else {
#pragma unroll
      for (int p2 = 0; p2 < 4; ++p2) {
        int n = (tid & 63) + ((p2 & 1) << 6);
        int kq = (tid >> 6) + ((p2 >> 1) << 2);
        short h0 = f2bf(wB[p2][0]), h1 = f2bf(wB[p2][1]);
        short h2 = f2bf(wB[p2][2]), h3 = f2bf(wB[p2][3]);
        short l0 = f2bf(wB[p2][0] - bf2f(h0)), l1 = f2bf(wB[p2][1] - bf2f(h1));
        short l2 = f2bf(wB[p2][2] - bf2f(h2)), l3 = f2bf(wB[p2][3] - bf2f(h3));
        int off = n * LDSW + ((((kq >> 1) ^ ((n >> 3) & 3)) << 3) + ((kq & 1) << 2));
        *(short4*)&sBh[off] = make_short4(h0, h1, h2, h3);
        *(short4*)&sBl[off] = make_short4(l0, l1, l2, l3);
      }
    }
    __syncthreads();
    if (k0 + 32 < K) {
      loadA(k0 + 32);
      loadB(k0 + 32);
    }
    const int ar = lane & 15;
    const int kc = lane >> 4;
    s16x8 fah[4], fal[4], fbh[4], fbl[4];
#pragma unroll
    for (int t2 = 0; t2 < 4; ++t2) {
      fah[t2] = *(const s16x8*)&sAh[swz(wm + (t2 << 4) + ar, kc)];
      fal[t2] = *(const s16x8*)&sAl[swz(wm + (t2 << 4) + ar, kc)];
      fbh[t2] = *(const s16x8*)&sBh[swz(wn + (t2 << 4) + ar, kc)];
      fbl[t2] = *(const s16x8*)&sBl[swz(wn + (t2 << 4) + ar, kc)];
    }
#pragma unroll
    for (int mi = 0; mi < 4; ++mi)
#pragma unroll
      for (int ni = 0; ni < 4; ++ni) {
        acc[mi][ni] = __builtin_amdgcn_mfma_f32_16x16x32_bf16(fah[mi], fbh[ni], acc[mi][ni], 0, 0, 0);
        acc[mi][ni] = __builtin_amdgcn_mfma_f32_16x16x32_bf16(fah[mi], fbl[ni], acc[mi][ni], 0, 0, 0);
        acc[mi][ni] = __builtin_amdgcn_mfma_f32_16x16x32_bf16(fal[mi], fbh[ni], acc[mi][ni], 0, 0, 0);
      }
  }

  const int erow = bm + wm + ((lane >> 4) << 2);
  const int ecol = bn + wn + (lane & 15);
  float bv[4];
#pragma unroll
  for (int ni = 0; ni < 4; ++ni) {
    int col = ecol + ni * 16;
    bv[ni] = (bias != nullptr && col < N) ? bias[col] : 0.f;
  }
#pragma unroll
  for (int mi = 0; mi < 4; ++mi) {
#pragma unroll
    for (int rr = 0; rr < 4; ++rr) {
      int row = erow + mi * 16 + rr;
      if (row >= M) continue;
#pragma unroll
      for (int ni = 0; ni < 4; ++ni) {
        int col = ecol + ni * 16;
        if (col >= N) continue;
        float v = acc[mi][ni][rr] + bv[ni];
        if (ACT == 1) v = gelu_f(v);
        size_t o = (size_t)row * N + col;
        if (WF32) Cf[o] = v;
        if (WBF16) {
          short hh = f2bf(v);
          Ch[o] = hh;
          Cl[o] = f2bf(v - bf2f(hh));
        }
      }
    }
  }
}

// ---------------- pack attention keep-mask into bits ----------------
__global__ __launch_bounds__(256) void maskpack_kernel(const float* __restrict__ mlog,
    unsigned* __restrict__ bits) {
  int idx = blockIdx.x * 256 + threadIdx.x;
  if (idx >= NQ * NWRD) return;
  int q = idx / NWRD, w = idx - q * NWRD;
  unsigned word = 0u;
  int c0 = w * 32;
#pragma unroll
  for (int b = 0; b < 32; ++b) {
    int c = c0 + b;
    unsigned keep;
    if (c < NQ + PFX) keep = 1u;
    else if (c < NT) keep = (mlog[(size_t)q * NPATCH + (c - NQ - PFX)] > 0.f) ? 1u : 0u;
    else keep = 0u;
    word |= keep << b;
  }
  bits[idx] = word;
}

// ---------------- flash attention, bf16x3 MFMA ----------------
// qkv in bf16 hi/lo (NT x 3072 each). Per block: 64 q-rows x 1 head, 4 waves.
// QK^T: Q A-frags from global; K row-major LDS (chunk-XOR swizzle).
// PV as O^T = V^T P^T: V transposed+packed u32 in LDS at staging; P packed per-wave.
__global__ __launch_bounds__(256, 2) void fattn_kernel(
    const short* __restrict__ qg_h, const short* __restrict__ qg_l,
    const unsigned* __restrict__ bits,
    short* __restrict__ ao_h, short* __restrict__ ao_l) {
  const int bid = blockIdx.x;
  const int h = bid & 15;           // head-major: same head -> same XCD locality
  const int q0 = (bid >> 4) * 64;
  const int tid = threadIdx.x;
  const int lane = tid & 63;
  const int w = tid >> 6;
  const int lg = lane >> 4;
  const int lc = lane & 15;

  __shared__ __align__(16) short Kh[64 * 64], Kl[64 * 64];
  __shared__ __align__(16) unsigned Vt[64 * 66];      // packed (vh | vl<<16), [d][kv]
  __shared__ __align__(16) unsigned Pp[4][16 * 66];   // per-wave packed P, [q][kv]
  __shared__ float fb[4][16];

  // Q A-fragments (row = q0+16w+lc, k = ks*32 + lg*8 + j)
  s16x8 qfh[2], qfl[2];
  {
    int gq = min(q0 + (w << 4) + lc, NT - 1);
    const size_t base = (size_t)gq * 3072 + h * 64;
#pragma unroll
    for (int ks = 0; ks < 2; ++ks) {
      qfh[ks] = *(const s16x8*)(qg_h + base + ks * 32 + (lg << 3));
      qfl[ks] = *(const s16x8*)(qg_l + base + ks * 32 + (lg << 3));
    }
  }

  const int krow = tid >> 3, kchk = tid & 7;
  const int vrow = tid >> 2, vchk = tid & 3;
  uint4 pkh[2], pkl[2], pvh[2], pvl[2];
  auto loadKV = [&](int kt) {
#pragma unroll
    for (int ii = 0; ii < 2; ++ii) {
      int gk = kt * 64 + krow + (ii << 5);
      if (gk < NT) {
        size_t b = (size_t)gk * 3072 + 1024 + h * 64 + (kchk << 3);
        pkh[ii] = *(const uint4*)(qg_h + b);
        pkl[ii] = *(const uint4*)(qg_l + b);
      } else {
        pkh[ii] = make_uint4(0, 0, 0, 0); pkl[ii] = make_uint4(0, 0, 0, 0);
      }
      int gv = kt * 64 + vrow;
      int vc = vchk + (ii << 2);
      if (gv < NT) {
        size_t b = (size_t)gv * 3072 + 2048 + h * 64 + (vc << 3);
        pvh[ii] = *(const uint4*)(qg_h + b);
        pvl[ii] = *(const uint4*)(qg_l + b);
      } else {
        pvh[ii] = make_uint4(0, 0, 0, 0); pvl[ii] = make_uint4(0, 0, 0, 0);
      }
    }
  };
  auto writeKV = [&]() {
#pragma unroll
    for (int ii = 0; ii < 2; ++ii) {
      int row = krow + (ii << 5);
      int off = (row << 6) + ((kchk ^ (row & 7)) << 3);
      *(uint4*)&Kh[off] = pkh[ii];
      *(uint4*)&Kl[off] = pkl[ii];
      int vc = vchk + (ii << 2);
      const unsigned* ph = (const unsigned*)&pvh[ii];
      const unsigned* pl = (const unsigned*)&pvl[ii];
#pragma unroll
      for (int jj = 0; jj < 8; ++jj) {
        unsigned hh = (jj & 1) ? (ph[jj >> 1] >> 16) : (ph[jj >> 1] & 0xffffu);
        unsigned ll = (jj & 1) ? (pl[jj >> 1] >> 16) : (pl[jj >> 1] & 0xffffu);
        Vt[((vc << 3) + jj) * 66 + vrow] = hh | (ll << 16);
      }
    }
  };
  auto ldpk = [&](const unsigned* base0, s16x8& fh, s16x8& fl) {
    union { s16x8 v; unsigned short e[8]; } H, L;
#pragma unroll
    for (int t = 0; t < 4; ++t) {
      uint2 u = *(const uint2*)(base0 + (t << 1));
      H.e[2 * t] = (unsigned short)(u.x & 0xffffu);
      L.e[2 * t] = (unsigned short)(u.x >> 16);
      H.e[2 * t + 1] = (unsigned short)(u.y & 0xffffu);
      L.e[2 * t + 1] = (unsigned short)(u.y >> 16);
    }
    fh = H.v; fl = L.v;
  };

  float rm_r[4], rl_r[4];
#pragma unroll
  for (int r = 0; r < 4; ++r) { rm_r[r] = -3.0e38f; rl_r[r] = 0.f; }
  f32x4 o_acc[4];
  {
    f32x4 z = {0.f, 0.f, 0.f, 0.f};
#pragma unroll
    for (int nd = 0; nd < 4; ++nd) o_acc[nd] = z;
  }

  loadKV(0);
  for (int kt = 0; kt < NKT; ++kt) {
    __syncthreads();
    writeKV();
    __syncthreads();
    if (kt + 1 < NKT) loadKV(kt + 1);

    // ---- QK^T ----
    f32x4 sc[4];
    {
      f32x4 z = {0.f, 0.f, 0.f, 0.f};
#pragma unroll
      for (int ni = 0; ni < 4; ++ni) sc[ni] = z;
    }
#pragma unroll
    for (int ni = 0; ni < 4; ++ni) {
#pragma unroll
      for (int ks = 0; ks < 2; ++ks) {
        int row = (ni << 4) + lc;
        int ch = ((ks << 2) + lg) ^ (row & 7);
        s16x8 kh = *(const s16x8*)&Kh[(row << 6) + (ch << 3)];
        s16x8 kl = *(const s16x8*)&Kl[(row << 6) + (ch << 3)];
        sc[ni] = __builtin_amdgcn_mfma_f32_16x16x32_bf16(qfh[ks], kh, sc[ni], 0, 0, 0);
        sc[ni] = __builtin_amdgcn_mfma_f32_16x16x32_bf16(qfh[ks], kl, sc[ni], 0, 0, 0);
        sc[ni] = __builtin_amdgcn_mfma_f32_16x16x32_bf16(qfl[ks], kh, sc[ni], 0, 0, 0);
      }
    }

    // ---- scale + mask + OOB ----
    unsigned wr0[4], wr1[4];
#pragma unroll
    for (int r = 0; r < 4; ++r) {
      int gq = q0 + (w << 4) + (lg << 2) + r;
      wr0[r] = 0xFFFFFFFFu; wr1[r] = 0xFFFFFFFFu;
      if (gq < NQ) {
        wr0[r] = bits[gq * NWRD + (kt << 1)];
        wr1[r] = ((kt << 1) + 1 < NWRD) ? bits[gq * NWRD + (kt << 1) + 1] : 0u;
      }
    }
    const int kvb = kt << 6;
#pragma unroll
    for (int ni = 0; ni < 4; ++ni) {
      int kv = kvb + (ni << 4) + lc;
      unsigned bitpos = ((ni & 1) << 4) + lc;
#pragma unroll
      for (int r = 0; r < 4; ++r) {
        float sv = sc[ni][r] * 0.125f;
        unsigned wd = (ni < 2) ? wr0[r] : wr1[r];
        if (!((wd >> bitpos) & 1u)) sv -= 1e9f;
        sc[ni][r] = (kv < NT) ? sv : -3.0e38f;
      }
    }

    // ---- online softmax (rows live in 16-lane groups) ----
    float fr[4];
#pragma unroll
    for (int r = 0; r < 4; ++r) {
      float tm = fmaxf(fmaxf(sc[0][r], sc[1][r]), fmaxf(sc[2][r], sc[3][r]));
#pragma unroll
      for (int m2 = 1; m2 < 16; m2 <<= 1) tm = fmaxf(tm, __shfl_xor(tm, m2, 64));
      float mnew = fmaxf(rm_r[r], tm);
      float f = __expf(rm_r[r] - mnew);
      float ps = 0.f;
#pragma unroll
      for (int ni = 0; ni < 4; ++ni) {
        float e = __expf(sc[ni][r] - mnew);
        sc[ni][r] = e;
        ps += e;
      }
#pragma unroll
      for (int m2 = 1; m2 < 16; m2 <<= 1) ps += __shfl_xor(ps, m2, 64);
      rm_r[r] = mnew;
      rl_r[r] = rl_r[r] * f + ps;
      fr[r] = f;
    }

    // ---- P -> per-wave LDS (packed hi|lo u32) ----
    unsigned* P = Pp[w];
#pragma unroll
    for (int ni = 0; ni < 4; ++ni) {
#pragma unroll
      for (int r = 0; r < 4; ++r) {
        float v = sc[ni][r];
        short hh = f2bf(v);
        short ll = f2bf(v - bf2f(hh));
        int qq = (lg << 2) + r;
        int col = (ni << 4) + lc;
        P[qq * 66 + col] = (unsigned)(unsigned short)hh | ((unsigned)(unsigned short)ll << 16);
      }
    }
    // broadcast per-q rescale factor across the wave (o rows are d, cols are q)
    if (lc == 0) {
#pragma unroll
      for (int r = 0; r < 4; ++r) fb[w][(lg << 2) + r] = fr[r];
    }
    float fq = fb[w][lc];
#pragma unroll
    for (int nd = 0; nd < 4; ++nd)
#pragma unroll
      for (int r = 0; r < 4; ++r) o_acc[nd][r] *= fq;

    // ---- PV: O^T = V^T @ P^T ----
    s16x8 pah[2], pal[2];
#pragma unroll
    for (int ks = 0; ks < 2; ++ks)
      ldpk(&P[lc * 66 + ks * 32 + (lg << 3)], pah[ks], pal[ks]);
#pragma unroll
    for (int nd = 0; nd < 4; ++nd) {
#pragma unroll
      for (int ks = 0; ks < 2; ++ks) {
        s16x8 vh, vl;
        ldpk(&Vt[((nd << 4) + lc) * 66 + ks * 32 + (lg << 3)], vh, vl);
        o_acc[nd] = __builtin_amdgcn_mfma_f32_16x16x32_bf16(vh, pah[ks], o_acc[nd], 0, 0, 0);
        o_acc[nd] = __builtin_amdgcn_mfma_f32_16x16x32_bf16(vh, pal[ks], o_acc[nd], 0, 0, 0);
        o_acc[nd] = __builtin_amdgcn_mfma_f32_16x16x32_bf16(vl, pah[ks], o_acc[nd], 0, 0, 0);
      }
    }
  }

  // ---- epilogue: normalize + store (O^T: row d = 16nd+4lg+rr, col q = lc) ----
  if (lc == 0) {
#pragma unroll
    for (int r = 0; r < 4; ++r) fb[w][(lg << 2) + r] = rl_r[r];
  }
  float inv = 1.0f / fb[w][lc];
  int gq = q0 + (w << 4) + lc;
  if (gq < NT) {
#pragma unroll
    for (int nd = 0; nd < 4; ++nd) {
      short hh[4], ll[4];
#pragma unroll
      for (int r = 0; r < 4; ++r) {
        float v = o_acc[nd][r] * inv;
        hh[r] = f2bf(v);
        ll[r] = f2bf(v - bf2f(hh[r]));
      }
      size_t o = (size_t)gq * DM + h * 64 + (nd << 4) + (lg << 2);
      *(short4*)(ao_h + o) = make_short4(hh[0], hh[1], hh[2], hh[3]);
      *(short4*)(ao_l + o) = make_short4(ll[0], ll[1], ll[2], ll[3]);
    }
  }
}

// ---------------- residual with layer-scale: x += ls * y ----------------
__global__ __launch_bounds__(256) void resid_kernel(float* __restrict__ x,
    const float* __restrict__ y, const float* __restrict__ ls) {
  int idx = blockIdx.x * 256 + threadIdx.x;
  if (idx >= NT * DM) return;
  int d = idx & (DM - 1);
  x[idx] = fmaf(ls[d], y[idx], x[idx]);
}

extern "C" void kernel_launch(void* const* d_in, const int* in_sizes, int n_in,
                              void* d_out, int out_size, void* d_ws, size_t ws_size,
                              hipStream_t stream) {
  const float* x_tokens = (const float*)d_in[0];
  const float* q_weight = (const float*)d_in[1];
  const float* norm_g   = (const float*)d_in[2];
  const float* norm_b   = (const float*)d_in[3];
  const float* class_W  = (const float*)d_in[4];
  const float* class_b  = (const float*)d_in[5];
  const float* mask_W1  = (const float*)d_in[6];
  const float* mask_b1  = (const float*)d_in[7];
  const float* mask_W2  = (const float*)d_in[8];
  const float* mask_b2  = (const float*)d_in[9];
  const float* mask_W3  = (const float*)d_in[10];
  const float* mask_b3  = (const float*)d_in[11];
  const float* ln1_g    = (const float*)d_in[12];
  const float* ln1_b    = (const float*)d_in[13];
  const float* ln2_g    = (const float*)d_in[14];
  const float* ln2_b    = (const float*)d_in[15];
  const float* qkv_W    = (const float*)d_in[16];
  const float* qkv_b    = (const float*)d_in[17];
  const float* proj_W   = (const float*)d_in[18];
  const float* proj_b   = (const float*)d_in[19];
  const float* ls1      = (const float*)d_in[20];
  const float* ls2      = (const float*)d_in[21];
  const float* fc1_W    = (const float*)d_in[22];
  const float* fc1_b    = (const float*)d_in[23];
  const float* fc2_W    = (const float*)d_in[24];
  const float* fc2_b    = (const float*)d_in[25];

  float* out = (float*)d_out;

  char* p = (char*)d_ws;
  auto alloc = [&](size_t bytes) {
    char* r = p;
    p += (bytes + 255) & ~(size_t)255;
    return r;
  };
  float* x      = (float*)alloc((size_t)NT * DM * 4);
  short* lnb_h  = (short*)alloc((size_t)NT * DM * 2);
  short* lnb_l  = (short*)alloc((size_t)NT * DM * 2);
  short* ao_h   = (short*)alloc((size_t)NT * DM * 2);
  short* ao_l   = (short*)alloc((size_t)NT * DM * 2);
  float* tmp    = (float*)alloc((size_t)NT * DM * 4);
  float* qkvbuf = (float*)alloc((size_t)NT * 3 * DM * 4);
  unsigned* bias_bits = (unsigned*)alloc((size_t)NQ * NWRD * 4);
  float* fc2o = (float*)ao_h;
  short* g1_h = (short*)tmp;
  short* g1_l = g1_h + (size_t)NT * 4 * DM;
  short* qkv_h = (short*)qkvbuf;                 // bf16 hi qkv (NT*3*DM)
  short* qkv_l = qkv_h + (size_t)NT * 3 * DM;    // bf16 lo qkv
  short* f1_h = (short*)qkvbuf;                  // predict scratch (dead vs qkv in time)
  short* f1_l = f1_h + (size_t)NQ * DM;
  short* f2_h = f1_l + (size_t)NQ * DM;
  short* f2_l = f2_h + (size_t)NQ * DM;
  short* f3_h = f2_l + (size_t)NQ * DM;
  short* f3_l = f3_h + (size_t)NQ * DM;

  const int ELEM_GRID = (NT * DM + 255) / 256;
  auto ggrid = [](int M, int Nc) { return dim3((Nc + 127) / 128, (M + 127) / 128); };

  concat_kernel<<<ELEM_GRID, 256, 0, stream>>>(q_weight, x_tokens, x);

  for (int i = 0; i <= NBLK; ++i) {
    ln_kernel<<<NT, 256, 0, stream>>>(x, norm_g, norm_b, lnb_h, lnb_l);
    float* mask_i = out + (size_t)i * NQ * NPATCH;
    float* cls_i  = out + (size_t)5 * NQ * NPATCH + (size_t)i * NQ * NCLS;
    mgemm_kernel<0, 1, 0, 1><<<ggrid(NQ, DM), 256, 0, stream>>>(
        lnb_h, lnb_l, mask_W1, nullptr, nullptr, mask_b1, nullptr, f1_h, f1_l, NQ, DM, DM);
    mgemm_kernel<0, 1, 0, 1><<<ggrid(NQ, DM), 256, 0, stream>>>(
        f1_h, f1_l, mask_W2, nullptr, nullptr, mask_b2, nullptr, f2_h, f2_l, NQ, DM, DM);
    mgemm_kernel<0, 0, 0, 1><<<ggrid(NQ, DM), 256, 0, stream>>>(
        f2_h, f2_l, mask_W3, nullptr, nullptr, mask_b3, nullptr, f3_h, f3_l, NQ, DM, DM);
    mgemm_kernel<1, 0, 1, 0><<<ggrid(NQ, NPATCH), 256, 0, stream>>>(
        f3_h, f3_l, nullptr, lnb_h + (size_t)(NQ + PFX) * DM, lnb_l + (size_t)(NQ + PFX) * DM,
        nullptr, mask_i, nullptr, nullptr, NQ, NPATCH, DM);
    mgemm_kernel<0, 0, 1, 0><<<ggrid(NQ, NCLS), 256, 0, stream>>>(
        lnb_h, lnb_l, class_W, nullptr, nullptr, class_b, cls_i, nullptr, nullptr, NQ, NCLS, DM);
    if (i == NBLK) break;

    ln_kernel<<<NT, 256, 0, stream>>>(x, ln1_g + i * DM, ln1_b + i * DM, lnb_h, lnb_l);
    mgemm_kernel<0, 0, 0, 1><<<ggrid(NT, 3 * DM), 256, 0, stream>>>(
        lnb_h, lnb_l, qkv_W + (size_t)i * DM * 3 * DM, nullptr, nullptr,
        qkv_b + i * 3 * DM, nullptr, qkv_h, qkv_l, NT, 3 * DM, DM);
    maskpack_kernel<<<(NQ * NWRD + 255) / 256, 256, 0, stream>>>(mask_i, bias_bits);
    fattn_kernel<<<NKT * NHEAD, 256, 0, stream>>>(qkv_h, qkv_l, bias_bits, ao_h, ao_l);
    mgemm_kernel<0, 0, 1, 0><<<ggrid(NT, DM), 256, 0, stream>>>(
        ao_h, ao_l, proj_W + (size_t)i * DM * DM, nullptr, nullptr,
        proj_b + i * DM, tmp, nullptr, nullptr, NT, DM, DM);
    resid_kernel<<<ELEM_GRID, 256, 0, stream>>>(x, tmp, ls1 + i * DM);
    ln_kernel<<<NT, 256, 0, stream>>>(x, ln2_g + i * DM, ln2_b + i * DM, lnb_h, lnb_l);
    mgemm_kernel<0, 1, 0, 1><<<ggrid(NT, 4 * DM), 256, 0, stream>>>(
        lnb_h, lnb_l, fc1_W + (size_t)i * DM * 4 * DM, nullptr, nullptr,
        fc1_b + i * 4 * DM, nullptr, g1_h, g1_l, NT, 4 * DM, DM);
    mgemm_kernel<0, 0, 1, 0><<<ggrid(NT, DM), 256, 0, stream>>>(
        g1_h, g1_l, fc2_W + (size_t)i * 4 * DM * DM, nullptr, nullptr,
        fc2_b + i * DM, fc2o, nullptr, nullptr, NT, DM, 4 * DM);
    resid_kernel<<<ELEM_GRID, 256, 0, stream>>>(x, fc2o, ls2 + i * DM);
  }
}

// Round 7
// 2879.921 us; speedup vs baseline: 8.8273x; 1.1454x over previous
//
#include <hip/hip_runtime.h>
#include <hip/hip_bf16.h>

#define NQ 200
#define PFX 5
#define NPATCH 1600
#define NT 1805
#define DM 1024
#define NHEAD 16
#define DHEAD 64
#define NBLK 4
#define NCLS 151
#define NKT 29     // ceil(1805/64)
#define NWRD 57    // ceil(1805/32) mask words per query row

typedef short s16x8 __attribute__((ext_vector_type(8)));
typedef float f32x4 __attribute__((ext_vector_type(4)));

__device__ __forceinline__ float gelu_f(float x) {
  return 0.5f * x * (1.0f + erff(x * 0.7071067811865476f));
}
__device__ __forceinline__ short f2bf(float x) {
  __hip_bfloat16 h = __float2bfloat16(x);
  return *reinterpret_cast<short*>(&h);
}
__device__ __forceinline__ float bf2f(short s) {
  __hip_bfloat16 h;
  *reinterpret_cast<short*>(&h) = s;
  return __bfloat162float(h);
}
// async 16B global->LDS (width literal 16). LDS dest must be wave-uniform base.
__device__ __forceinline__ void glds16(const void* g, void* l) {
  __builtin_amdgcn_global_load_lds(
      (const __attribute__((address_space(1))) void*)g,
      (__attribute__((address_space(3))) void*)l, 16, 0, 0);
}

// ---------------- concat: x = [q_weight ; x_tokens] ----------------
__global__ __launch_bounds__(256) void concat_kernel(const float* __restrict__ qw,
    const float* __restrict__ xt, float* __restrict__ x) {
  int idx = blockIdx.x * 256 + threadIdx.x;
  if (idx >= NT * DM) return;
  int n = idx >> 10;
  x[idx] = (n < NQ) ? qw[idx] : xt[idx - NQ * DM];
}

// ---------------- LayerNorm -> bf16 hi/lo ----------------
__global__ __launch_bounds__(256) void ln_kernel(const float* __restrict__ in,
    const float* __restrict__ g, const float* __restrict__ b,
    short* __restrict__ oh, short* __restrict__ ol) {
  const int row = blockIdx.x;
  const int tid = threadIdx.x;
  const float* x = in + (size_t)row * DM;
  float v[4];
#pragma unroll
  for (int i = 0; i < 4; ++i) v[i] = x[tid + (i << 8)];
  float s = v[0] + v[1] + v[2] + v[3];
  __shared__ float red[4];
  __shared__ float red2[4];
#pragma unroll
  for (int off = 32; off; off >>= 1) s += __shfl_down(s, off, 64);
  if ((tid & 63) == 0) red[tid >> 6] = s;
  __syncthreads();
  float mean = (red[0] + red[1] + red[2] + red[3]) * (1.0f / DM);
  float sq = 0.f;
#pragma unroll
  for (int i = 0; i < 4; ++i) { float d = v[i] - mean; sq += d * d; }
#pragma unroll
  for (int off = 32; off; off >>= 1) sq += __shfl_down(sq, off, 64);
  if ((tid & 63) == 0) red2[tid >> 6] = sq;
  __syncthreads();
  float var = (red2[0] + red2[1] + red2[2] + red2[3]) * (1.0f / DM);
  float inv = 1.0f / sqrtf(var + 1e-6f);
#pragma unroll
  for (int i = 0; i < 4; ++i) {
    int d = tid + (i << 8);
    float y = (v[i] - mean) * inv * g[d] + b[d];
    short hh = f2bf(y);
    oh[(size_t)row * DM + d] = hh;
    ol[(size_t)row * DM + d] = f2bf(y - bf2f(hh));
  }
}

// ---------------- bf16x3 MFMA GEMM v2: dbuf LDS, 1 barrier/K-step ----------------
// A: bf16 hi/lo M x K row-major, staged via global_load_lds (inverse-swz source).
// B: BSRC==0: fp32 K x N (transpose+split reg-staged, issue-early/write-late)
//    BSRC==1: bf16 hi/lo N x K (global_load_lds like A)
// LDS rows: 32 shorts (64B) = 4 x 16B chunks; physical chunk = logical ^ ((row>>1)&3).
template <int BM64, int BSRC, int ACT, int WF32, int WBF16>
__global__ __launch_bounds__(256) void mgemm_kernel(
    const short* __restrict__ Ah, const short* __restrict__ Al,
    const float* __restrict__ Wf,
    const short* __restrict__ Bh, const short* __restrict__ Bl,
    const float* __restrict__ bias,
    float* __restrict__ Cf, short* __restrict__ Ch, short* __restrict__ Cl,
    int M, int N, int K) {
  constexpr int BM = BM64 ? 64 : 128;
  constexpr int AT = BM64 ? 2 : 4;       // A-frag repeats per wave
  constexpr int AISS = BM64 ? 1 : 2;     // glds issues per wave per A array
  __shared__ __align__(16) short sAh[2 * BM * 32], sAl[2 * BM * 32];
  __shared__ __align__(16) short sBh[2 * 128 * 32], sBl[2 * 128 * 32];
  const int tid = threadIdx.x;
  const int lane = tid & 63;
  const int w = tid >> 6;
  const int bm = blockIdx.y * BM;
  const int bn = blockIdx.x << 7;

  f32x4 acc[AT][4];
  {
    f32x4 z = {0.f, 0.f, 0.f, 0.f};
#pragma unroll
    for (int mi = 0; mi < AT; ++mi)
#pragma unroll
      for (int ni = 0; ni < 4; ++ni) acc[mi][ni] = z;
  }

  // ---- stagers ----
  auto issueA = [&](int buf, int k0) {
#pragma unroll
    for (int i = 0; i < AISS; ++i) {
      int br = (BM64 ? (w << 4) : (w << 5) + (i << 4));          // wave base row
      int r = br + (lane >> 2);
      int cg = (lane & 3) ^ ((r >> 1) & 3);
      size_t go = (size_t)min(bm + r, M - 1) * K + k0 + (cg << 3);
      glds16(Ah + go, &sAh[(buf * BM + br) * 32]);
      glds16(Al + go, &sAl[(buf * BM + br) * 32]);
    }
  };
  auto issueB1 = [&](int buf, int k0) {  // BSRC==1 path
#pragma unroll
    for (int i = 0; i < 2; ++i) {
      int br = (w << 5) + (i << 4);
      int r = br + (lane >> 2);
      int cg = (lane & 3) ^ ((r >> 1) & 3);
      size_t go = (size_t)min(bn + r, N - 1) * K + k0 + (cg << 3);
      glds16(Bh + go, &sBh[(buf * 128 + br) * 32]);
      glds16(Bl + go, &sBl[(buf * 128 + br) * 32]);
    }
  };
  float wv[2][8];
  auto loadB0 = [&](int k0) {  // BSRC==0: fp32 weights, transpose read
#pragma unroll
    for (int p = 0; p < 2; ++p) {
      int n = tid & 127;
      int c8 = (tid >> 7) + (p << 1);
      const float* Wp = Wf + (size_t)(k0 + (c8 << 3)) * N + min(bn + n, N - 1);
#pragma unroll
      for (int j = 0; j < 8; ++j) wv[p][j] = Wp[(size_t)j * N];
    }
  };
  auto writeB0 = [&](int buf) {
#pragma unroll
    for (int p = 0; p < 2; ++p) {
      int n = tid & 127;
      int c8 = (tid >> 7) + (p << 1);
      int cp = c8 ^ ((n >> 1) & 3);
      union { uint4 u; short e[8]; } H, L;
#pragma unroll
      for (int j = 0; j < 8; ++j) {
        short hh = f2bf(wv[p][j]);
        H.e[j] = hh;
        L.e[j] = f2bf(wv[p][j] - bf2f(hh));
      }
      int off = (buf * 128 + n) * 32 + (cp << 3);
      *(uint4*)&sBh[off] = H.u;
      *(uint4*)&sBl[off] = L.u;
    }
  };

  // ---- prologue: tile 0 into buf 0 ----
  issueA(0, 0);
  if (BSRC == 1) issueB1(0, 0);
  else { loadB0(0); writeB0(0); }
  __syncthreads();

  const int nt = K >> 5;
  int cur = 0;
  const int ar = lane & 15;
  const int kc = lane >> 4;
  const int wmr = BM64 ? ((w >> 1) << 5) : ((w >> 1) << 6);
  const int wnr = (w & 1) << 6;

  for (int t = 0; t < nt; ++t) {
    const bool more = (t + 1 < nt);
    if (more) {  // issue next tile early; lands during MFMA phase
      int k0n = (t + 1) << 5;
      issueA(cur ^ 1, k0n);
      if (BSRC == 1) issueB1(cur ^ 1, k0n);
      else loadB0(k0n);
    }
    // ---- fragments (swizzled ds_read_b128) + MFMA ----
    s16x8 fah[AT], fal[AT], fbh[4], fbl[4];
#pragma unroll
    for (int t2 = 0; t2 < AT; ++t2) {
      int r = wmr + (t2 << 4) + ar;
      int off = (cur * BM + r) * 32 + ((kc ^ ((r >> 1) & 3)) << 3);
      fah[t2] = *(const s16x8*)&sAh[off];
      fal[t2] = *(const s16x8*)&sAl[off];
    }
#pragma unroll
    for (int t2 = 0; t2 < 4; ++t2) {
      int r = wnr + (t2 << 4) + ar;
      int off = (cur * 128 + r) * 32 + ((kc ^ ((r >> 1) & 3)) << 3);
      fbh[t2] = *(const s16x8*)&sBh[off];
      fbl[t2] = *(const s16x8*)&sBl[off];
    }
#pragma unroll
    for (int mi = 0; mi < AT; ++mi)
#pragma unroll
      for (int ni = 0; ni < 4; ++ni) {
        acc[mi][ni] = __builtin_amdgcn_mfma_f32_16x16x32_bf16(fah[mi], fbh[ni], acc[mi][ni], 0, 0, 0);
        acc[mi][ni] = __builtin_amdgcn_mfma_f32_16x16x32_bf16(fah[mi], fbl[ni], acc[mi][ni], 0, 0, 0);
        acc[mi][ni] = __builtin_amdgcn_mfma_f32_16x16x32_bf16(fal[mi], fbh[ni], acc[mi][ni], 0, 0, 0);
      }
    if (more) {
      if (BSRC == 0) writeB0(cur ^ 1);  // waits only on wv loads
      __syncthreads();                  // drains glds (vmcnt) + publishes LDS
      cur ^= 1;
    }
  }

  // ---- epilogue ----
  const int erow = bm + wmr + ((lane >> 4) << 2);
  const int ecol = bn + wnr + (lane & 15);
  float bv[4];
#pragma unroll
  for (int ni = 0; ni < 4; ++ni) {
    int col = ecol + ni * 16;
    bv[ni] = (bias != nullptr && col < N) ? bias[col] : 0.f;
  }
#pragma unroll
  for (int mi = 0; mi < AT; ++mi) {
#pragma unroll
    for (int rr = 0; rr < 4; ++rr) {
      int row = erow + mi * 16 + rr;
      if (row >= M) continue;
#pragma unroll
      for (int ni = 0; ni < 4; ++ni) {
        int col = ecol + ni * 16;
        if (col >= N) continue;
        float v = acc[mi][ni][rr] + bv[ni];
        if (ACT == 1) v = gelu_f(v);
        size_t o = (size_t)row * N + col;
        if (WF32) Cf[o] = v;
        if (WBF16) {
          short hh = f2bf(v);
          Ch[o] = hh;
          Cl[o] = f2bf(v - bf2f(hh));
        }
      }
    }
  }
}

// ---------------- pack attention keep-mask into bits ----------------
__global__ __launch_bounds__(256) void maskpack_kernel(const float* __restrict__ mlog,
    unsigned* __restrict__ bits) {
  int idx = blockIdx.x * 256 + threadIdx.x;
  if (idx >= NQ * NWRD) return;
  int q = idx / NWRD, w = idx - q * NWRD;
  unsigned word = 0u;
  int c0 = w * 32;
#pragma unroll
  for (int b = 0; b < 32; ++b) {
    int c = c0 + b;
    unsigned keep;
    if (c < NQ + PFX) keep = 1u;
    else if (c < NT) keep = (mlog[(size_t)q * NPATCH + (c - NQ - PFX)] > 0.f) ? 1u : 0u;
    else keep = 0u;
    word |= keep << b;
  }
  bits[idx] = word;
}

// ---------------- flash attention, bf16x3 MFMA ----------------
__global__ __launch_bounds__(256, 2) void fattn_kernel(
    const short* __restrict__ qg_h, const short* __restrict__ qg_l,
    const unsigned* __restrict__ bits,
    short* __restrict__ ao_h, short* __restrict__ ao_l) {
  const int bid = blockIdx.x;
  const int h = bid & 15;
  const int q0 = (bid >> 4) * 64;
  const int tid = threadIdx.x;
  const int lane = tid & 63;
  const int w = tid >> 6;
  const int lg = lane >> 4;
  const int lc = lane & 15;

  __shared__ __align__(16) short Kh[64 * 64], Kl[64 * 64];
  __shared__ __align__(16) unsigned Vt[64 * 66];
  __shared__ __align__(16) unsigned Pp[4][16 * 66];
  __shared__ float fb[4][16];

  s16x8 qfh[2], qfl[2];
  {
    int gq = min(q0 + (w << 4) + lc, NT - 1);
    const size_t base = (size_t)gq * 3072 + h * 64;
#pragma unroll
    for (int ks = 0; ks < 2; ++ks) {
      qfh[ks] = *(const s16x8*)(qg_h + base + ks * 32 + (lg << 3));
      qfl[ks] = *(const s16x8*)(qg_l + base + ks * 32 + (lg << 3));
    }
  }

  const int krow = tid >> 3, kchk = tid & 7;
  const int vrow = tid >> 2, vchk = tid & 3;
  uint4 pkh[2], pkl[2], pvh[2], pvl[2];
  auto loadKV = [&](int kt) {
#pragma unroll
    for (int ii = 0; ii < 2; ++ii) {
      int gk = kt * 64 + krow + (ii << 5);
      if (gk < NT) {
        size_t b = (size_t)gk * 3072 + 1024 + h * 64 + (kchk << 3);
        pkh[ii] = *(const uint4*)(qg_h + b);
        pkl[ii] = *(const uint4*)(qg_l + b);
      } else {
        pkh[ii] = make_uint4(0, 0, 0, 0); pkl[ii] = make_uint4(0, 0, 0, 0);
      }
      int gv = kt * 64 + vrow;
      int vc = vchk + (ii << 2);
      if (gv < NT) {
        size_t b = (size_t)gv * 3072 + 2048 + h * 64 + (vc << 3);
        pvh[ii] = *(const uint4*)(qg_h + b);
        pvl[ii] = *(const uint4*)(qg_l + b);
      } else {
        pvh[ii] = make_uint4(0, 0, 0, 0); pvl[ii] = make_uint4(0, 0, 0, 0);
      }
    }
  };
  auto writeKV = [&]() {
#pragma unroll
    for (int ii = 0; ii < 2; ++ii) {
      int row = krow + (ii << 5);
      int off = (row << 6) + ((kchk ^ (row & 7)) << 3);
      *(uint4*)&Kh[off] = pkh[ii];
      *(uint4*)&Kl[off] = pkl[ii];
      int vc = vchk + (ii << 2);
      const unsigned* ph = (const unsigned*)&pvh[ii];
      const unsigned* pl = (const unsigned*)&pvl[ii];
#pragma unroll
      for (int jj = 0; jj < 8; ++jj) {
        unsigned hh = (jj & 1) ? (ph[jj >> 1] >> 16) : (ph[jj >> 1] & 0xffffu);
        unsigned ll = (jj & 1) ? (pl[jj >> 1] >> 16) : (pl[jj >> 1] & 0xffffu);
        Vt[((vc << 3) + jj) * 66 + vrow] = hh | (ll << 16);
      }
    }
  };
  auto ldpk = [&](const unsigned* base0, s16x8& fh, s16x8& fl) {
    union { s16x8 v; unsigned short e[8]; } H, L;
#pragma unroll
    for (int t = 0; t < 4; ++t) {
      uint2 u = *(const uint2*)(base0 + (t << 1));
      H.e[2 * t] = (unsigned short)(u.x & 0xffffu);
      L.e[2 * t] = (unsigned short)(u.x >> 16);
      H.e[2 * t + 1] = (unsigned short)(u.y & 0xffffu);
      L.e[2 * t + 1] = (unsigned short)(u.y >> 16);
    }
    fh = H.v; fl = L.v;
  };

  float rm_r[4], rl_r[4];
#pragma unroll
  for (int r = 0; r < 4; ++r) { rm_r[r] = -3.0e38f; rl_r[r] = 0.f; }
  f32x4 o_acc[4];
  {
    f32x4 z = {0.f, 0.f, 0.f, 0.f};
#pragma unroll
    for (int nd = 0; nd < 4; ++nd) o_acc[nd] = z;
  }

  loadKV(0);
  for (int kt = 0; kt < NKT; ++kt) {
    __syncthreads();
    writeKV();
    __syncthreads();
    if (kt + 1 < NKT) loadKV(kt + 1);

    f32x4 sc[4];
    {
      f32x4 z = {0.f, 0.f, 0.f, 0.f};
#pragma unroll
      for (int ni = 0; ni < 4; ++ni) sc[ni] = z;
    }
#pragma unroll
    for (int ni = 0; ni < 4; ++ni) {
#pragma unroll
      for (int ks = 0; ks < 2; ++ks) {
        int row = (ni << 4) + lc;
        int ch = ((ks << 2) + lg) ^ (row & 7);
        s16x8 kh = *(const s16x8*)&Kh[(row << 6) + (ch << 3)];
        s16x8 kl = *(const s16x8*)&Kl[(row << 6) + (ch << 3)];
        sc[ni] = __builtin_amdgcn_mfma_f32_16x16x32_bf16(qfh[ks], kh, sc[ni], 0, 0, 0);
        sc[ni] = __builtin_amdgcn_mfma_f32_16x16x32_bf16(qfh[ks], kl, sc[ni], 0, 0, 0);
        sc[ni] = __builtin_amdgcn_mfma_f32_16x16x32_bf16(qfl[ks], kh, sc[ni], 0, 0, 0);
      }
    }

    unsigned wr0[4], wr1[4];
#pragma unroll
    for (int r = 0; r < 4; ++r) {
      int gq = q0 + (w << 4) + (lg << 2) + r;
      wr0[r] = 0xFFFFFFFFu; wr1[r] = 0xFFFFFFFFu;
      if (gq < NQ) {
        wr0[r] = bits[gq * NWRD + (kt << 1)];
        wr1[r] = ((kt << 1) + 1 < NWRD) ? bits[gq * NWRD + (kt << 1) + 1] : 0u;
      }
    }
    const int kvb = kt << 6;
#pragma unroll
    for (int ni = 0; ni < 4; ++ni) {
      int kv = kvb + (ni << 4) + lc;
      unsigned bitpos = ((ni & 1) << 4) + lc;
#pragma unroll
      for (int r = 0; r < 4; ++r) {
        float sv = sc[ni][r] * 0.125f;
        unsigned wd = (ni < 2) ? wr0[r] : wr1[r];
        if (!((wd >> bitpos) & 1u)) sv -= 1e9f;
        sc[ni][r] = (kv < NT) ? sv : -3.0e38f;
      }
    }

    float fr[4];
#pragma unroll
    for (int r = 0; r < 4; ++r) {
      float tm = fmaxf(fmaxf(sc[0][r], sc[1][r]), fmaxf(sc[2][r], sc[3][r]));
#pragma unroll
      for (int m2 = 1; m2 < 16; m2 <<= 1) tm = fmaxf(tm, __shfl_xor(tm, m2, 64));
      float mnew = fmaxf(rm_r[r], tm);
      float f = __expf(rm_r[r] - mnew);
      float ps = 0.f;
#pragma unroll
      for (int ni = 0; ni < 4; ++ni) {
        float e = __expf(sc[ni][r] - mnew);
        sc[ni][r] = e;
        ps += e;
      }
#pragma unroll
      for (int m2 = 1; m2 < 16; m2 <<= 1) ps += __shfl_xor(ps, m2, 64);
      rm_r[r] = mnew;
      rl_r[r] = rl_r[r] * f + ps;
      fr[r] = f;
    }

    unsigned* P = Pp[w];
#pragma unroll
    for (int ni = 0; ni < 4; ++ni) {
#pragma unroll
      for (int r = 0; r < 4; ++r) {
        float v = sc[ni][r];
        short hh = f2bf(v);
        short ll = f2bf(v - bf2f(hh));
        int qq = (lg << 2) + r;
        int col = (ni << 4) + lc;
        P[qq * 66 + col] = (unsigned)(unsigned short)hh | ((unsigned)(unsigned short)ll << 16);
      }
    }
    if (lc == 0) {
#pragma unroll
      for (int r = 0; r < 4; ++r) fb[w][(lg << 2) + r] = fr[r];
    }
    float fq = fb[w][lc];
#pragma unroll
    for (int nd = 0; nd < 4; ++nd)
#pragma unroll
      for (int r = 0; r < 4; ++r) o_acc[nd][r] *= fq;

    s16x8 pah[2], pal[2];
#pragma unroll
    for (int ks = 0; ks < 2; ++ks)
      ldpk(&P[lc * 66 + ks * 32 + (lg << 3)], pah[ks], pal[ks]);
#pragma unroll
    for (int nd = 0; nd < 4; ++nd) {
#pragma unroll
      for (int ks = 0; ks < 2; ++ks) {
        s16x8 vh, vl;
        ldpk(&Vt[((nd << 4) + lc) * 66 + ks * 32 + (lg << 3)], vh, vl);
        o_acc[nd] = __builtin_amdgcn_mfma_f32_16x16x32_bf16(vh, pah[ks], o_acc[nd], 0, 0, 0);
        o_acc[nd] = __builtin_amdgcn_mfma_f32_16x16x32_bf16(vh, pal[ks], o_acc[nd], 0, 0, 0);
        o_acc[nd] = __builtin_amdgcn_mfma_f32_16x16x32_bf16(vl, pah[ks], o_acc[nd], 0, 0, 0);
      }
    }
  }

  if (lc == 0) {
#pragma unroll
    for (int r = 0; r < 4; ++r) fb[w][(lg << 2) + r] = rl_r[r];
  }
  float inv = 1.0f / fb[w][lc];
  int gq = q0 + (w << 4) + lc;
  if (gq < NT) {
#pragma unroll
    for (int nd = 0; nd < 4; ++nd) {
      short hh[4], ll[4];
#pragma unroll
      for (int r = 0; r < 4; ++r) {
        float v = o_acc[nd][r] * inv;
        hh[r] = f2bf(v);
        ll[r] = f2bf(v - bf2f(hh[r]));
      }
      size_t o = (size_t)gq * DM + h * 64 + (nd << 4) + (lg << 2);
      *(short4*)(ao_h + o) = make_short4(hh[0], hh[1], hh[2], hh[3]);
      *(short4*)(ao_l + o) = make_short4(ll[0], ll[1], ll[2], ll[3]);
    }
  }
}

// ---------------- residual with layer-scale: x += ls * y ----------------
__global__ __launch_bounds__(256) void resid_kernel(float* __restrict__ x,
    const float* __restrict__ y, const float* __restrict__ ls) {
  int idx = blockIdx.x * 256 + threadIdx.x;
  if (idx >= NT * DM) return;
  int d = idx & (DM - 1);
  x[idx] = fmaf(ls[d], y[idx], x[idx]);
}

extern "C" void kernel_launch(void* const* d_in, const int* in_sizes, int n_in,
                              void* d_out, int out_size, void* d_ws, size_t ws_size,
                              hipStream_t stream) {
  const float* x_tokens = (const float*)d_in[0];
  const float* q_weight = (const float*)d_in[1];
  const float* norm_g   = (const float*)d_in[2];
  const float* norm_b   = (const float*)d_in[3];
  const float* class_W  = (const float*)d_in[4];
  const float* class_b  = (const float*)d_in[5];
  const float* mask_W1  = (const float*)d_in[6];
  const float* mask_b1  = (const float*)d_in[7];
  const float* mask_W2  = (const float*)d_in[8];
  const float* mask_b2  = (const float*)d_in[9];
  const float* mask_W3  = (const float*)d_in[10];
  const float* mask_b3  = (const float*)d_in[11];
  const float* ln1_g    = (const float*)d_in[12];
  const float* ln1_b    = (const float*)d_in[13];
  const float* ln2_g    = (const float*)d_in[14];
  const float* ln2_b    = (const float*)d_in[15];
  const float* qkv_W    = (const float*)d_in[16];
  const float* qkv_b    = (const float*)d_in[17];
  const float* proj_W   = (const float*)d_in[18];
  const float* proj_b   = (const float*)d_in[19];
  const float* ls1      = (const float*)d_in[20];
  const float* ls2      = (const float*)d_in[21];
  const float* fc1_W    = (const float*)d_in[22];
  const float* fc1_b    = (const float*)d_in[23];
  const float* fc2_W    = (const float*)d_in[24];
  const float* fc2_b    = (const float*)d_in[25];

  float* out = (float*)d_out;

  char* p = (char*)d_ws;
  auto alloc = [&](size_t bytes) {
    char* r = p;
    p += (bytes + 255) & ~(size_t)255;
    return r;
  };
  float* x      = (float*)alloc((size_t)NT * DM * 4);
  short* lnb_h  = (short*)alloc((size_t)NT * DM * 2);
  short* lnb_l  = (short*)alloc((size_t)NT * DM * 2);
  short* ao_h   = (short*)alloc((size_t)NT * DM * 2);
  short* ao_l   = (short*)alloc((size_t)NT * DM * 2);
  float* tmp    = (float*)alloc((size_t)NT * DM * 4);
  float* qkvbuf = (float*)alloc((size_t)NT * 3 * DM * 4);
  unsigned* bias_bits = (unsigned*)alloc((size_t)NQ * NWRD * 4);
  float* fc2o = (float*)ao_h;
  short* g1_h = (short*)tmp;
  short* g1_l = g1_h + (size_t)NT * 4 * DM;
  short* qkv_h = (short*)qkvbuf;
  short* qkv_l = qkv_h + (size_t)NT * 3 * DM;
  short* f1_h = (short*)qkvbuf;
  short* f1_l = f1_h + (size_t)NQ * DM;
  short* f2_h = f1_l + (size_t)NQ * DM;
  short* f2_l = f2_h + (size_t)NQ * DM;
  short* f3_h = f2_l + (size_t)NQ * DM;
  short* f3_l = f3_h + (size_t)NQ * DM;

  const int ELEM_GRID = (NT * DM + 255) / 256;
  auto g128 = [](int M, int Nc) { return dim3((Nc + 127) / 128, (M + 127) / 128); };
  auto g64  = [](int M, int Nc) { return dim3((Nc + 127) / 128, (M + 63) / 64); };

  concat_kernel<<<ELEM_GRID, 256, 0, stream>>>(q_weight, x_tokens, x);

  for (int i = 0; i <= NBLK; ++i) {
    ln_kernel<<<NT, 256, 0, stream>>>(x, norm_g, norm_b, lnb_h, lnb_l);
    float* mask_i = out + (size_t)i * NQ * NPATCH;
    float* cls_i  = out + (size_t)5 * NQ * NPATCH + (size_t)i * NQ * NCLS;
    mgemm_kernel<1, 0, 1, 0, 1><<<g64(NQ, DM), 256, 0, stream>>>(
        lnb_h, lnb_l, mask_W1, nullptr, nullptr, mask_b1, nullptr, f1_h, f1_l, NQ, DM, DM);
    mgemm_kernel<1, 0, 1, 0, 1><<<g64(NQ, DM), 256, 0, stream>>>(
        f1_h, f1_l, mask_W2, nullptr, nullptr, mask_b2, nullptr, f2_h, f2_l, NQ, DM, DM);
    mgemm_kernel<1, 0, 0, 0, 1><<<g64(NQ, DM), 256, 0, stream>>>(
        f2_h, f2_l, mask_W3, nullptr, nullptr, mask_b3, nullptr, f3_h, f3_l, NQ, DM, DM);
    mgemm_kernel<1, 1, 0, 1, 0><<<g64(NQ, NPATCH), 256, 0, stream>>>(
        f3_h, f3_l, nullptr, lnb_h + (size_t)(NQ + PFX) * DM, lnb_l + (size_t)(NQ + PFX) * DM,
        nullptr, mask_i, nullptr, nullptr, NQ, NPATCH, DM);
    mgemm_kernel<1, 0, 0, 1, 0><<<g64(NQ, NCLS), 256, 0, stream>>>(
        lnb_h, lnb_l, class_W, nullptr, nullptr, class_b, cls_i, nullptr, nullptr, NQ, NCLS, DM);
    if (i == NBLK) break;

    ln_kernel<<<NT, 256, 0, stream>>>(x, ln1_g + i * DM, ln1_b + i * DM, lnb_h, lnb_l);
    mgemm_kernel<0, 0, 0, 0, 1><<<g128(NT, 3 * DM), 256, 0, stream>>>(
        lnb_h, lnb_l, qkv_W + (size_t)i * DM * 3 * DM, nullptr, nullptr,
        qkv_b + i * 3 * DM, nullptr, qkv_h, qkv_l, NT, 3 * DM, DM);
    maskpack_kernel<<<(NQ * NWRD + 255) / 256, 256, 0, stream>>>(mask_i, bias_bits);
    fattn_kernel<<<NKT * NHEAD, 256, 0, stream>>>(qkv_h, qkv_l, bias_bits, ao_h, ao_l);
    mgemm_kernel<1, 0, 0, 1, 0><<<g64(NT, DM), 256, 0, stream>>>(
        ao_h, ao_l, proj_W + (size_t)i * DM * DM, nullptr, nullptr,
        proj_b + i * DM, tmp, nullptr, nullptr, NT, DM, DM);
    resid_kernel<<<ELEM_GRID, 256, 0, stream>>>(x, tmp, ls1 + i * DM);
    ln_kernel<<<NT, 256, 0, stream>>>(x, ln2_g + i * DM, ln2_b + i * DM, lnb_h, lnb_l);
    mgemm_kernel<0, 0, 1, 0, 1><<<g128(NT, 4 * DM), 256, 0, stream>>>(
        lnb_h, lnb_l, fc1_W + (size_t)i * DM * 4 * DM, nullptr, nullptr,
        fc1_b + i * 4 * DM, nullptr, g1_h, g1_l, NT, 4 * DM, DM);
    mgemm_kernel<1, 0, 0, 1, 0><<<g64(NT, DM), 256, 0, stream>>>(
        g1_h, g1_l, fc2_W + (size_t)i * 4 * DM * DM, nullptr, nullptr,
        fc2_b + i * DM, fc2o, nullptr, nullptr, NT, DM, 4 * DM);
    resid_kernel<<<ELEM_GRID, 256, 0, stream>>>(x, fc2o, ls2 + i * DM);
  }
}

// Round 8
// 2351.668 us; speedup vs baseline: 10.8101x; 1.2246x over previous
//
#include <hip/hip_runtime.h>
#include <hip/hip_bf16.h>

#define NQ 200
#define PFX 5
#define NPATCH 1600
#define NT 1805
#define DM 1024
#define NHEAD 16
#define DHEAD 64
#define NBLK 4
#define NCLS 151
#define NKT 29     // ceil(1805/64)
#define NWRD 57    // ceil(1805/32) mask words per query row

typedef short s16x8 __attribute__((ext_vector_type(8)));
typedef float f32x4 __attribute__((ext_vector_type(4)));

__device__ __forceinline__ float gelu_f(float x) {
  return 0.5f * x * (1.0f + erff(x * 0.7071067811865476f));
}
__device__ __forceinline__ short f2bf(float x) {
  __hip_bfloat16 h = __float2bfloat16(x);
  return *reinterpret_cast<short*>(&h);
}
__device__ __forceinline__ float bf2f(short s) {
  __hip_bfloat16 h;
  *reinterpret_cast<short*>(&h) = s;
  return __bfloat162float(h);
}
// async 16B global->LDS (width literal 16). LDS dest must be wave-uniform base.
__device__ __forceinline__ void glds16(const void* g, void* l) {
  __builtin_amdgcn_global_load_lds(
      (const __attribute__((address_space(1))) void*)g,
      (__attribute__((address_space(3))) void*)l, 16, 0, 0);
}

// ---------------- concat: x = [q_weight ; x_tokens] ----------------
__global__ __launch_bounds__(256) void concat_kernel(const float* __restrict__ qw,
    const float* __restrict__ xt, float* __restrict__ x) {
  int idx = blockIdx.x * 256 + threadIdx.x;
  if (idx >= NT * DM) return;
  int n = idx >> 10;
  x[idx] = (n < NQ) ? qw[idx] : xt[idx - NQ * DM];
}

// ---------------- LayerNorm -> bf16 hi/lo ----------------
__global__ __launch_bounds__(256) void ln_kernel(const float* __restrict__ in,
    const float* __restrict__ g, const float* __restrict__ b,
    short* __restrict__ oh, short* __restrict__ ol) {
  const int row = blockIdx.x;
  const int tid = threadIdx.x;
  const float* x = in + (size_t)row * DM;
  float v[4];
#pragma unroll
  for (int i = 0; i < 4; ++i) v[i] = x[tid + (i << 8)];
  float s = v[0] + v[1] + v[2] + v[3];
  __shared__ float red[4];
  __shared__ float red2[4];
#pragma unroll
  for (int off = 32; off; off >>= 1) s += __shfl_down(s, off, 64);
  if ((tid & 63) == 0) red[tid >> 6] = s;
  __syncthreads();
  float mean = (red[0] + red[1] + red[2] + red[3]) * (1.0f / DM);
  float sq = 0.f;
#pragma unroll
  for (int i = 0; i < 4; ++i) { float d = v[i] - mean; sq += d * d; }
#pragma unroll
  for (int off = 32; off; off >>= 1) sq += __shfl_down(sq, off, 64);
  if ((tid & 63) == 0) red2[tid >> 6] = sq;
  __syncthreads();
  float var = (red2[0] + red2[1] + red2[2] + red2[3]) * (1.0f / DM);
  float inv = 1.0f / sqrtf(var + 1e-6f);
#pragma unroll
  for (int i = 0; i < 4; ++i) {
    int d = tid + (i << 8);
    float y = (v[i] - mean) * inv * g[d] + b[d];
    short hh = f2bf(y);
    oh[(size_t)row * DM + d] = hh;
    ol[(size_t)row * DM + d] = f2bf(y - bf2f(hh));
  }
}

// ---------------- bf16x3 MFMA GEMM v3: dbuf LDS + split-K ----------------
// A: bf16 hi/lo M x K row-major (global_load_lds, inverse-swz source).
// B: BSRC==0: fp32 K x N (transpose+split reg-staged, issue-early/write-late)
//    BSRC==1: bf16 hi/lo N x K (global_load_lds)
// OMODE: 0 = bf16 h/l out (+ACT); 1 = fp32 out (+ACT);
//        2 = atomicAdd fp32 (bias on z==0, no act);
//        3 = partial fp32 store at Cf + z*M*N (bias on z==0, no act).
template <int BM64, int BSRC, int ACT, int OMODE, int KS>
__global__ __launch_bounds__(256) void mgemm_kernel(
    const short* __restrict__ Ah, const short* __restrict__ Al,
    const float* __restrict__ Wf,
    const short* __restrict__ Bh, const short* __restrict__ Bl,
    const float* __restrict__ bias,
    float* __restrict__ Cf, short* __restrict__ Ch, short* __restrict__ Cl,
    int M, int N, int K) {
  constexpr int BM = BM64 ? 64 : 128;
  constexpr int AT = BM64 ? 2 : 4;
  constexpr int AISS = BM64 ? 1 : 2;
  __shared__ __align__(16) short sAh[2 * BM * 32], sAl[2 * BM * 32];
  __shared__ __align__(16) short sBh[2 * 128 * 32], sBl[2 * 128 * 32];
  const int tid = threadIdx.x;
  const int lane = tid & 63;
  const int w = tid >> 6;
  const int bm = blockIdx.y * BM;
  const int bn = blockIdx.x << 7;
  const int z = (KS > 1) ? blockIdx.z : 0;
  const int KL = K / KS;
  const int kbase = z * KL;

  f32x4 acc[AT][4];
  {
    f32x4 zf = {0.f, 0.f, 0.f, 0.f};
#pragma unroll
    for (int mi = 0; mi < AT; ++mi)
#pragma unroll
      for (int ni = 0; ni < 4; ++ni) acc[mi][ni] = zf;
  }

  auto issueA = [&](int buf, int k0) {
#pragma unroll
    for (int i = 0; i < AISS; ++i) {
      int br = (BM64 ? (w << 4) : (w << 5) + (i << 4));
      int r = br + (lane >> 2);
      int cg = (lane & 3) ^ ((r >> 1) & 3);
      size_t go = (size_t)min(bm + r, M - 1) * K + kbase + k0 + (cg << 3);
      glds16(Ah + go, &sAh[(buf * BM + br) * 32]);
      glds16(Al + go, &sAl[(buf * BM + br) * 32]);
    }
  };
  auto issueB1 = [&](int buf, int k0) {
#pragma unroll
    for (int i = 0; i < 2; ++i) {
      int br = (w << 5) + (i << 4);
      int r = br + (lane >> 2);
      int cg = (lane & 3) ^ ((r >> 1) & 3);
      size_t go = (size_t)min(bn + r, N - 1) * K + kbase + k0 + (cg << 3);
      glds16(Bh + go, &sBh[(buf * 128 + br) * 32]);
      glds16(Bl + go, &sBl[(buf * 128 + br) * 32]);
    }
  };
  float wv[2][8];
  auto loadB0 = [&](int k0) {
#pragma unroll
    for (int p = 0; p < 2; ++p) {
      int n = tid & 127;
      int c8 = (tid >> 7) + (p << 1);
      const float* Wp = Wf + (size_t)(kbase + k0 + (c8 << 3)) * N + min(bn + n, N - 1);
#pragma unroll
      for (int j = 0; j < 8; ++j) wv[p][j] = Wp[(size_t)j * N];
    }
  };
  auto writeB0 = [&](int buf) {
#pragma unroll
    for (int p = 0; p < 2; ++p) {
      int n = tid & 127;
      int c8 = (tid >> 7) + (p << 1);
      int cp = c8 ^ ((n >> 1) & 3);
      union { uint4 u; short e[8]; } H, L;
#pragma unroll
      for (int j = 0; j < 8; ++j) {
        short hh = f2bf(wv[p][j]);
        H.e[j] = hh;
        L.e[j] = f2bf(wv[p][j] - bf2f(hh));
      }
      int off = (buf * 128 + n) * 32 + (cp << 3);
      *(uint4*)&sBh[off] = H.u;
      *(uint4*)&sBl[off] = L.u;
    }
  };

  issueA(0, 0);
  if (BSRC == 1) issueB1(0, 0);
  else { loadB0(0); writeB0(0); }
  __syncthreads();

  const int nt = KL >> 5;
  int cur = 0;
  const int ar = lane & 15;
  const int kc = lane >> 4;
  const int wmr = BM64 ? ((w >> 1) << 5) : ((w >> 1) << 6);
  const int wnr = (w & 1) << 6;

  for (int t = 0; t < nt; ++t) {
    const bool more = (t + 1 < nt);
    if (more) {
      int k0n = (t + 1) << 5;
      issueA(cur ^ 1, k0n);
      if (BSRC == 1) issueB1(cur ^ 1, k0n);
      else loadB0(k0n);
    }
    s16x8 fah[AT], fal[AT], fbh[4], fbl[4];
#pragma unroll
    for (int t2 = 0; t2 < AT; ++t2) {
      int r = wmr + (t2 << 4) + ar;
      int off = (cur * BM + r) * 32 + ((kc ^ ((r >> 1) & 3)) << 3);
      fah[t2] = *(const s16x8*)&sAh[off];
      fal[t2] = *(const s16x8*)&sAl[off];
    }
#pragma unroll
    for (int t2 = 0; t2 < 4; ++t2) {
      int r = wnr + (t2 << 4) + ar;
      int off = (cur * 128 + r) * 32 + ((kc ^ ((r >> 1) & 3)) << 3);
      fbh[t2] = *(const s16x8*)&sBh[off];
      fbl[t2] = *(const s16x8*)&sBl[off];
    }
#pragma unroll
    for (int mi = 0; mi < AT; ++mi)
#pragma unroll
      for (int ni = 0; ni < 4; ++ni) {
        acc[mi][ni] = __builtin_amdgcn_mfma_f32_16x16x32_bf16(fah[mi], fbh[ni], acc[mi][ni], 0, 0, 0);
        acc[mi][ni] = __builtin_amdgcn_mfma_f32_16x16x32_bf16(fah[mi], fbl[ni], acc[mi][ni], 0, 0, 0);
        acc[mi][ni] = __builtin_amdgcn_mfma_f32_16x16x32_bf16(fal[mi], fbh[ni], acc[mi][ni], 0, 0, 0);
      }
    if (more) {
      if (BSRC == 0) writeB0(cur ^ 1);
      __syncthreads();
      cur ^= 1;
    }
  }

  // ---- epilogue ----
  const int erow = bm + wmr + ((lane >> 4) << 2);
  const int ecol = bn + wnr + (lane & 15);
  float bv[4];
#pragma unroll
  for (int ni = 0; ni < 4; ++ni) {
    int col = ecol + ni * 16;
    float b0 = (bias != nullptr && col < N) ? bias[col] : 0.f;
    bv[ni] = (KS > 1 && z != 0) ? 0.f : b0;
  }
#pragma unroll
  for (int mi = 0; mi < AT; ++mi) {
#pragma unroll
    for (int rr = 0; rr < 4; ++rr) {
      int row = erow + mi * 16 + rr;
      if (row >= M) continue;
#pragma unroll
      for (int ni = 0; ni < 4; ++ni) {
        int col = ecol + ni * 16;
        if (col >= N) continue;
        float v = acc[mi][ni][rr] + bv[ni];
        size_t o = (size_t)row * N + col;
        if (OMODE == 0) {
          if (ACT == 1) v = gelu_f(v);
          short hh = f2bf(v);
          Ch[o] = hh;
          Cl[o] = f2bf(v - bf2f(hh));
        } else if (OMODE == 1) {
          if (ACT == 1) v = gelu_f(v);
          Cf[o] = v;
        } else if (OMODE == 2) {
          atomicAdd(&Cf[o], v);
        } else {  // OMODE == 3
          Cf[(size_t)z * M * N + o] = v;
        }
      }
    }
  }
}

// ---------------- split-K partial reduce (+act, +bf16 hi/lo split) ----------------
template <int ACT, int WSPLIT>
__global__ __launch_bounds__(256) void redsplit_kernel(const float* __restrict__ pb,
    float* __restrict__ outf, short* __restrict__ oh, short* __restrict__ ol,
    int KSr, int MN) {
  int idx = blockIdx.x * 256 + threadIdx.x;
  if (idx >= MN) return;
  float s = 0.f;
  for (int zz = 0; zz < KSr; ++zz) s += pb[(size_t)zz * MN + idx];
  if (ACT == 1) s = gelu_f(s);
  if (WSPLIT) {
    short hh = f2bf(s);
    oh[idx] = hh;
    ol[idx] = f2bf(s - bf2f(hh));
  } else {
    outf[idx] = s;
  }
}

// ---------------- pack attention keep-mask into bits ----------------
__global__ __launch_bounds__(256) void maskpack_kernel(const float* __restrict__ mlog,
    unsigned* __restrict__ bits) {
  int idx = blockIdx.x * 256 + threadIdx.x;
  if (idx >= NQ * NWRD) return;
  int q = idx / NWRD, w = idx - q * NWRD;
  unsigned word = 0u;
  int c0 = w * 32;
#pragma unroll
  for (int b = 0; b < 32; ++b) {
    int c = c0 + b;
    unsigned keep;
    if (c < NQ + PFX) keep = 1u;
    else if (c < NT) keep = (mlog[(size_t)q * NPATCH + (c - NQ - PFX)] > 0.f) ? 1u : 0u;
    else keep = 0u;
    word |= keep << b;
  }
  bits[idx] = word;
}

// ---------------- flash attention, bf16x3 MFMA, fp32 qkv input ----------------
__global__ __launch_bounds__(256, 2) void fattn_kernel(
    const float* __restrict__ qkv, const unsigned* __restrict__ bits,
    short* __restrict__ ao_h, short* __restrict__ ao_l) {
  const int bid = blockIdx.x;
  const int h = bid & 15;
  const int q0 = (bid >> 4) * 64;
  const int tid = threadIdx.x;
  const int lane = tid & 63;
  const int w = tid >> 6;
  const int lg = lane >> 4;
  const int lc = lane & 15;

  __shared__ __align__(16) short Kh[64 * 64], Kl[64 * 64];
  __shared__ __align__(16) unsigned Vt[64 * 66];
  __shared__ __align__(16) unsigned Pp[4][16 * 66];
  __shared__ float fb[4][16];

  s16x8 qfh[2], qfl[2];
  {
    int gq = min(q0 + (w << 4) + lc, NT - 1);
    const float* qp = qkv + (size_t)gq * 3072 + h * 64;
#pragma unroll
    for (int ks = 0; ks < 2; ++ks) {
      union { s16x8 v; short e[8]; } H, L;
#pragma unroll
      for (int j = 0; j < 8; ++j) {
        float f = qp[ks * 32 + (lg << 3) + j];
        short hh = f2bf(f);
        H.e[j] = hh;
        L.e[j] = f2bf(f - bf2f(hh));
      }
      qfh[ks] = H.v;
      qfl[ks] = L.v;
    }
  }

  const int krow = tid >> 3, kchk = tid & 7;
  const int vrow = tid >> 2, vchk = tid & 3;
  float4 pk[2][2], pv[2][2];
  auto loadKV = [&](int kt) {
#pragma unroll
    for (int ii = 0; ii < 2; ++ii) {
      int gk = kt * 64 + krow + (ii << 5);
      if (gk < NT) {
        const float* b = qkv + (size_t)gk * 3072 + 1024 + h * 64 + (kchk << 3);
        pk[ii][0] = *(const float4*)b;
        pk[ii][1] = *(const float4*)(b + 4);
      } else {
        pk[ii][0] = make_float4(0.f, 0.f, 0.f, 0.f);
        pk[ii][1] = pk[ii][0];
      }
      int gv = kt * 64 + vrow;
      int vc = vchk + (ii << 2);
      if (gv < NT) {
        const float* b = qkv + (size_t)gv * 3072 + 2048 + h * 64 + (vc << 3);
        pv[ii][0] = *(const float4*)b;
        pv[ii][1] = *(const float4*)(b + 4);
      } else {
        pv[ii][0] = make_float4(0.f, 0.f, 0.f, 0.f);
        pv[ii][1] = pv[ii][0];
      }
    }
  };
  auto writeKV = [&]() {
#pragma unroll
    for (int ii = 0; ii < 2; ++ii) {
      int row = krow + (ii << 5);
      int off = (row << 6) + ((kchk ^ (row & 7)) << 3);
      union { uint4 u; short e[8]; } H, L;
      const float* kf = (const float*)&pk[ii][0];
#pragma unroll
      for (int j = 0; j < 8; ++j) {
        short hh = f2bf(kf[j]);
        H.e[j] = hh;
        L.e[j] = f2bf(kf[j] - bf2f(hh));
      }
      *(uint4*)&Kh[off] = H.u;
      *(uint4*)&Kl[off] = L.u;
      int vc = vchk + (ii << 2);
      const float* vf = (const float*)&pv[ii][0];
#pragma unroll
      for (int jj = 0; jj < 8; ++jj) {
        short hh = f2bf(vf[jj]);
        short ll = f2bf(vf[jj] - bf2f(hh));
        Vt[((vc << 3) + jj) * 66 + vrow] =
            (unsigned)(unsigned short)hh | ((unsigned)(unsigned short)ll << 16);
      }
    }
  };
  auto ldpk = [&](const unsigned* base0, s16x8& fh, s16x8& fl) {
    union { s16x8 v; unsigned short e[8]; } H, L;
#pragma unroll
    for (int t = 0; t < 4; ++t) {
      uint2 u = *(const uint2*)(base0 + (t << 1));
      H.e[2 * t] = (unsigned short)(u.x & 0xffffu);
      L.e[2 * t] = (unsigned short)(u.x >> 16);
      H.e[2 * t + 1] = (unsigned short)(u.y & 0xffffu);
      L.e[2 * t + 1] = (unsigned short)(u.y >> 16);
    }
    fh = H.v; fl = L.v;
  };

  float rm_r[4], rl_r[4];
#pragma unroll
  for (int r = 0; r < 4; ++r) { rm_r[r] = -3.0e38f; rl_r[r] = 0.f; }
  f32x4 o_acc[4];
  {
    f32x4 zf = {0.f, 0.f, 0.f, 0.f};
#pragma unroll
    for (int nd = 0; nd < 4; ++nd) o_acc[nd] = zf;
  }

  loadKV(0);
  for (int kt = 0; kt < NKT; ++kt) {
    __syncthreads();
    writeKV();
    __syncthreads();
    if (kt + 1 < NKT) loadKV(kt + 1);

    f32x4 sc[4];
    {
      f32x4 zf = {0.f, 0.f, 0.f, 0.f};
#pragma unroll
      for (int ni = 0; ni < 4; ++ni) sc[ni] = zf;
    }
#pragma unroll
    for (int ni = 0; ni < 4; ++ni) {
#pragma unroll
      for (int ks = 0; ks < 2; ++ks) {
        int row = (ni << 4) + lc;
        int ch = ((ks << 2) + lg) ^ (row & 7);
        s16x8 kh = *(const s16x8*)&Kh[(row << 6) + (ch << 3)];
        s16x8 kl = *(const s16x8*)&Kl[(row << 6) + (ch << 3)];
        sc[ni] = __builtin_amdgcn_mfma_f32_16x16x32_bf16(qfh[ks], kh, sc[ni], 0, 0, 0);
        sc[ni] = __builtin_amdgcn_mfma_f32_16x16x32_bf16(qfh[ks], kl, sc[ni], 0, 0, 0);
        sc[ni] = __builtin_amdgcn_mfma_f32_16x16x32_bf16(qfl[ks], kh, sc[ni], 0, 0, 0);
      }
    }

    unsigned wr0[4], wr1[4];
#pragma unroll
    for (int r = 0; r < 4; ++r) {
      int gq = q0 + (w << 4) + (lg << 2) + r;
      wr0[r] = 0xFFFFFFFFu; wr1[r] = 0xFFFFFFFFu;
      if (gq < NQ) {
        wr0[r] = bits[gq * NWRD + (kt << 1)];
        wr1[r] = ((kt << 1) + 1 < NWRD) ? bits[gq * NWRD + (kt << 1) + 1] : 0u;
      }
    }
    const int kvb = kt << 6;
#pragma unroll
    for (int ni = 0; ni < 4; ++ni) {
      int kv = kvb + (ni << 4) + lc;
      unsigned bitpos = ((ni & 1) << 4) + lc;
#pragma unroll
      for (int r = 0; r < 4; ++r) {
        float sv = sc[ni][r] * 0.125f;
        unsigned wd = (ni < 2) ? wr0[r] : wr1[r];
        if (!((wd >> bitpos) & 1u)) sv -= 1e9f;
        sc[ni][r] = (kv < NT) ? sv : -3.0e38f;
      }
    }

    float fr[4];
#pragma unroll
    for (int r = 0; r < 4; ++r) {
      float tm = fmaxf(fmaxf(sc[0][r], sc[1][r]), fmaxf(sc[2][r], sc[3][r]));
#pragma unroll
      for (int m2 = 1; m2 < 16; m2 <<= 1) tm = fmaxf(tm, __shfl_xor(tm, m2, 64));
      float mnew = fmaxf(rm_r[r], tm);
      float f = __expf(rm_r[r] - mnew);
      float ps = 0.f;
#pragma unroll
      for (int ni = 0; ni < 4; ++ni) {
        float e = __expf(sc[ni][r] - mnew);
        sc[ni][r] = e;
        ps += e;
      }
#pragma unroll
      for (int m2 = 1; m2 < 16; m2 <<= 1) ps += __shfl_xor(ps, m2, 64);
      rm_r[r] = mnew;
      rl_r[r] = rl_r[r] * f + ps;
      fr[r] = f;
    }

    unsigned* P = Pp[w];
#pragma unroll
    for (int ni = 0; ni < 4; ++ni) {
#pragma unroll
      for (int r = 0; r < 4; ++r) {
        float v = sc[ni][r];
        short hh = f2bf(v);
        short ll = f2bf(v - bf2f(hh));
        int qq = (lg << 2) + r;
        int col = (ni << 4) + lc;
        P[qq * 66 + col] = (unsigned)(unsigned short)hh | ((unsigned)(unsigned short)ll << 16);
      }
    }
    if (lc == 0) {
#pragma unroll
      for (int r = 0; r < 4; ++r) fb[w][(lg << 2) + r] = fr[r];
    }
    float fq = fb[w][lc];
#pragma unroll
    for (int nd = 0; nd < 4; ++nd)
#pragma unroll
      for (int r = 0; r < 4; ++r) o_acc[nd][r] *= fq;

    s16x8 pah[2], pal[2];
#pragma unroll
    for (int ks = 0; ks < 2; ++ks)
      ldpk(&P[lc * 66 + ks * 32 + (lg << 3)], pah[ks], pal[ks]);
#pragma unroll
    for (int nd = 0; nd < 4; ++nd) {
#pragma unroll
      for (int ks = 0; ks < 2; ++ks) {
        s16x8 vh, vl;
        ldpk(&Vt[((nd << 4) + lc) * 66 + ks * 32 + (lg << 3)], vh, vl);
        o_acc[nd] = __builtin_amdgcn_mfma_f32_16x16x32_bf16(vh, pah[ks], o_acc[nd], 0, 0, 0);
        o_acc[nd] = __builtin_amdgcn_mfma_f32_16x16x32_bf16(vh, pal[ks], o_acc[nd], 0, 0, 0);
        o_acc[nd] = __builtin_amdgcn_mfma_f32_16x16x32_bf16(vl, pah[ks], o_acc[nd], 0, 0, 0);
      }
    }
  }

  if (lc == 0) {
#pragma unroll
    for (int r = 0; r < 4; ++r) fb[w][(lg << 2) + r] = rl_r[r];
  }
  float inv = 1.0f / fb[w][lc];
  int gq = q0 + (w << 4) + lc;
  if (gq < NT) {
#pragma unroll
    for (int nd = 0; nd < 4; ++nd) {
      short hh[4], ll[4];
#pragma unroll
      for (int r = 0; r < 4; ++r) {
        float v = o_acc[nd][r] * inv;
        hh[r] = f2bf(v);
        ll[r] = f2bf(v - bf2f(hh[r]));
      }
      size_t o = (size_t)gq * DM + h * 64 + (nd << 4) + (lg << 2);
      *(short4*)(ao_h + o) = make_short4(hh[0], hh[1], hh[2], hh[3]);
      *(short4*)(ao_l + o) = make_short4(ll[0], ll[1], ll[2], ll[3]);
    }
  }
}

// ---------------- residual with layer-scale: x += ls * y ----------------
__global__ __launch_bounds__(256) void resid_kernel(float* __restrict__ x,
    const float* __restrict__ y, const float* __restrict__ ls) {
  int idx = blockIdx.x * 256 + threadIdx.x;
  if (idx >= NT * DM) return;
  int d = idx & (DM - 1);
  x[idx] = fmaf(ls[d], y[idx], x[idx]);
}

extern "C" void kernel_launch(void* const* d_in, const int* in_sizes, int n_in,
                              void* d_out, int out_size, void* d_ws, size_t ws_size,
                              hipStream_t stream) {
  const float* x_tokens = (const float*)d_in[0];
  const float* q_weight = (const float*)d_in[1];
  const float* norm_g   = (const float*)d_in[2];
  const float* norm_b   = (const float*)d_in[3];
  const float* class_W  = (const float*)d_in[4];
  const float* class_b  = (const float*)d_in[5];
  const float* mask_W1  = (const float*)d_in[6];
  const float* mask_b1  = (const float*)d_in[7];
  const float* mask_W2  = (const float*)d_in[8];
  const float* mask_b2  = (const float*)d_in[9];
  const float* mask_W3  = (const float*)d_in[10];
  const float* mask_b3  = (const float*)d_in[11];
  const float* ln1_g    = (const float*)d_in[12];
  const float* ln1_b    = (const float*)d_in[13];
  const float* ln2_g    = (const float*)d_in[14];
  const float* ln2_b    = (const float*)d_in[15];
  const float* qkv_W    = (const float*)d_in[16];
  const float* qkv_b    = (const float*)d_in[17];
  const float* proj_W   = (const float*)d_in[18];
  const float* proj_b   = (const float*)d_in[19];
  const float* ls1      = (const float*)d_in[20];
  const float* ls2      = (const float*)d_in[21];
  const float* fc1_W    = (const float*)d_in[22];
  const float* fc1_b    = (const float*)d_in[23];
  const float* fc2_W    = (const float*)d_in[24];
  const float* fc2_b    = (const float*)d_in[25];

  float* out = (float*)d_out;

  char* p = (char*)d_ws;
  auto alloc = [&](size_t bytes) {
    char* r = p;
    p += (bytes + 255) & ~(size_t)255;
    return r;
  };
  float* x      = (float*)alloc((size_t)NT * DM * 4);
  short* lnb_h  = (short*)alloc((size_t)NT * DM * 2);
  short* lnb_l  = (short*)alloc((size_t)NT * DM * 2);
  short* ao_h   = (short*)alloc((size_t)NT * DM * 2);  // also: split-K partials, fc2o
  short* ao_l   = (short*)alloc((size_t)NT * DM * 2);
  float* tmp    = (float*)alloc((size_t)NT * DM * 4);
  float* qkvbuf = (float*)alloc((size_t)NT * 3 * DM * 4);
  unsigned* bias_bits = (unsigned*)alloc((size_t)NQ * NWRD * 4);
  float* fc2o = (float*)ao_h;                       // NT*DM fp32 (== ao region)
  float* pbuf = (float*)ao_h;                       // split-K partials (<= 7.39 MB)
  short* g1_h = (short*)tmp;                        // fc1 out h (NT*4DM)
  short* g1_l = g1_h + (size_t)NT * 4 * DM;         // fc1 out l (ends at qkvbuf end)
  short* f1_h = (short*)qkvbuf;                     // predict scratch in dead qkvbuf
  short* f1_l = f1_h + (size_t)NQ * DM;
  short* f2_h = f1_l + (size_t)NQ * DM;
  short* f2_l = f2_h + (size_t)NQ * DM;
  short* f3_h = f2_l + (size_t)NQ * DM;
  short* f3_l = f3_h + (size_t)NQ * DM;

  const int ELEM_GRID = (NT * DM + 255) / 256;
  auto g128 = [](int M, int Nc, int ks) { return dim3((Nc + 127) / 128, (M + 127) / 128, ks); };
  auto g64  = [](int M, int Nc, int ks) { return dim3((Nc + 127) / 128, (M + 63) / 64, ks); };
  auto rgrid = [](int n) { return dim3((n + 255) / 256); };

  concat_kernel<<<ELEM_GRID, 256, 0, stream>>>(q_weight, x_tokens, x);

  for (int i = 0; i <= NBLK; ++i) {
    // ---- predict head on shared-norm LN(x) ----
    ln_kernel<<<NT, 256, 0, stream>>>(x, norm_g, norm_b, lnb_h, lnb_l);
    float* mask_i = out + (size_t)i * NQ * NPATCH;
    float* cls_i  = out + (size_t)5 * NQ * NPATCH + (size_t)i * NQ * NCLS;
    // mask chain: deterministic split-K (partials in ao region) + reduce/gelu/split
    mgemm_kernel<1, 0, 0, 3, 8><<<g64(NQ, DM, 8), 256, 0, stream>>>(
        lnb_h, lnb_l, mask_W1, nullptr, nullptr, mask_b1, pbuf, nullptr, nullptr, NQ, DM, DM);
    redsplit_kernel<1, 1><<<rgrid(NQ * DM), 256, 0, stream>>>(pbuf, nullptr, f1_h, f1_l, 8, NQ * DM);
    mgemm_kernel<1, 0, 0, 3, 8><<<g64(NQ, DM, 8), 256, 0, stream>>>(
        f1_h, f1_l, mask_W2, nullptr, nullptr, mask_b2, pbuf, nullptr, nullptr, NQ, DM, DM);
    redsplit_kernel<1, 1><<<rgrid(NQ * DM), 256, 0, stream>>>(pbuf, nullptr, f2_h, f2_l, 8, NQ * DM);
    mgemm_kernel<1, 0, 0, 3, 8><<<g64(NQ, DM, 8), 256, 0, stream>>>(
        f2_h, f2_l, mask_W3, nullptr, nullptr, mask_b3, pbuf, nullptr, nullptr, NQ, DM, DM);
    redsplit_kernel<0, 1><<<rgrid(NQ * DM), 256, 0, stream>>>(pbuf, nullptr, f3_h, f3_l, 8, NQ * DM);
    // einsum: deterministic split-K partials -> mask_i
    mgemm_kernel<1, 1, 0, 3, 4><<<g64(NQ, NPATCH, 4), 256, 0, stream>>>(
        f3_h, f3_l, nullptr, lnb_h + (size_t)(NQ + PFX) * DM, lnb_l + (size_t)(NQ + PFX) * DM,
        nullptr, pbuf, nullptr, nullptr, NQ, NPATCH, DM);
    redsplit_kernel<0, 0><<<rgrid(NQ * NPATCH), 256, 0, stream>>>(
        pbuf, mask_i, nullptr, nullptr, 4, NQ * NPATCH);
    // class logits: deterministic split-K partials -> cls_i
    mgemm_kernel<1, 0, 0, 3, 8><<<g64(NQ, NCLS, 8), 256, 0, stream>>>(
        lnb_h, lnb_l, class_W, nullptr, nullptr, class_b, pbuf, nullptr, nullptr, NQ, NCLS, DM);
    redsplit_kernel<0, 0><<<rgrid(NQ * NCLS), 256, 0, stream>>>(
        pbuf, cls_i, nullptr, nullptr, 8, NQ * NCLS);
    if (i == NBLK) break;

    // ---- transformer block i ----
    ln_kernel<<<NT, 256, 0, stream>>>(x, ln1_g + i * DM, ln1_b + i * DM, lnb_h, lnb_l);
    hipMemsetAsync(qkvbuf, 0, (size_t)NT * 3 * DM * 4, stream);
    mgemm_kernel<0, 0, 0, 2, 2><<<g128(NT, 3 * DM, 2), 256, 0, stream>>>(
        lnb_h, lnb_l, qkv_W + (size_t)i * DM * 3 * DM, nullptr, nullptr,
        qkv_b + i * 3 * DM, qkvbuf, nullptr, nullptr, NT, 3 * DM, DM);
    maskpack_kernel<<<(NQ * NWRD + 255) / 256, 256, 0, stream>>>(mask_i, bias_bits);
    fattn_kernel<<<NKT * NHEAD, 256, 0, stream>>>(qkvbuf, bias_bits, ao_h, ao_l);
    hipMemsetAsync(tmp, 0, (size_t)NT * DM * 4, stream);
    mgemm_kernel<1, 0, 0, 2, 4><<<g64(NT, DM, 4), 256, 0, stream>>>(
        ao_h, ao_l, proj_W + (size_t)i * DM * DM, nullptr, nullptr,
        proj_b + i * DM, tmp, nullptr, nullptr, NT, DM, DM);
    resid_kernel<<<ELEM_GRID, 256, 0, stream>>>(x, tmp, ls1 + i * DM);
    ln_kernel<<<NT, 256, 0, stream>>>(x, ln2_g + i * DM, ln2_b + i * DM, lnb_h, lnb_l);
    mgemm_kernel<0, 0, 1, 0, 1><<<g128(NT, 4 * DM, 1), 256, 0, stream>>>(
        lnb_h, lnb_l, fc1_W + (size_t)i * DM * 4 * DM, nullptr, nullptr,
        fc1_b + i * 4 * DM, nullptr, g1_h, g1_l, NT, 4 * DM, DM);
    hipMemsetAsync(fc2o, 0, (size_t)NT * DM * 4, stream);
    mgemm_kernel<1, 0, 0, 2, 4><<<g64(NT, DM, 4), 256, 0, stream>>>(
        g1_h, g1_l, fc2_W + (size_t)i * 4 * DM * DM, nullptr, nullptr,
        fc2_b + i * DM, fc2o, nullptr, nullptr, NT, DM, 4 * DM);
    resid_kernel<<<ELEM_GRID, 256, 0, stream>>>(x, fc2o, ls2 + i * DM);
  }
}